// Round 16
// baseline (970.773 us; speedup 1.0000x reference)
//
#include <hip/hip_runtime.h>
#include <hip/hip_bf16.h>

// B=16, T=2048, D=2048, K(msg)=4, C=128, KC=512, CODEBOOK=512
#define M_BT      32768
#define KC_DIM    512
#define D_DIM     2048
#define C_DIM     128
#define NROWS     131072
#define NCODES    512
#define NELEM     16777216   // NROWS*C_DIM
#define GAP_EPS   6.0e-4f
#define FLT_BIG   3.4028235e38f

typedef __bf16 bf16x8 __attribute__((ext_vector_type(8)));
typedef float  f32x4  __attribute__((ext_vector_type(4)));

#define AS3(p) ((__attribute__((address_space(3))) void*)(p))
#define AS1(p) ((const __attribute__((address_space(1))) void*)(p))

static __device__ __forceinline__ ushort f2bf(float x) {
    unsigned u = __float_as_uint(x);
    unsigned r = (u + 0x7fffu + ((u >> 16) & 1u)) >> 16;
    return (ushort)r;
}
static __device__ __forceinline__ float bf2f(ushort u) {
    return __uint_as_float(((unsigned)u) << 16);
}

// shared MFMA compute macro: 16 frag-pairs x 3 products from dbuf plane p
#define MFMA_COMPUTE(p) do {                                                          \
    bf16x8 ah[4], al[4], bh[4], bl[4];                                                \
    _Pragma("unroll")                                                                 \
    for (int mi = 0; mi < 4; ++mi) {                                                  \
        const int off = (wm * 64 + mi * 16 + fr) * 32 + s4 * 8;                       \
        ah[mi] = *(const bf16x8*)&Ahs[p][off];                                        \
        al[mi] = *(const bf16x8*)&Als[p][off];                                        \
    }                                                                                 \
    _Pragma("unroll")                                                                 \
    for (int ni = 0; ni < 4; ++ni) {                                                  \
        const int off = (wn * 64 + ni * 16 + fr) * 32 + s4 * 8;                       \
        bh[ni] = *(const bf16x8*)&Bhs[p][off];                                        \
        bl[ni] = *(const bf16x8*)&Bls[p][off];                                        \
    }                                                                                 \
    _Pragma("unroll")                                                                 \
    for (int mi = 0; mi < 4; ++mi)                                                    \
        _Pragma("unroll")                                                             \
        for (int ni = 0; ni < 4; ++ni) {                                              \
            acc[mi][ni] = __builtin_amdgcn_mfma_f32_16x16x32_bf16(ah[mi], bh[ni], acc[mi][ni], 0, 0, 0); \
            acc[mi][ni] = __builtin_amdgcn_mfma_f32_16x16x32_bf16(ah[mi], bl[ni], acc[mi][ni], 0, 0, 0); \
            acc[mi][ni] = __builtin_amdgcn_mfma_f32_16x16x32_bf16(al[mi], bh[ni], acc[mi][ni], 0, 0, 0); \
        }                                                                             \
} while (0)

// ---------------- zero counters ----------------
__global__ __launch_bounds__(512)
void zero_kernel(unsigned* __restrict__ counts, float* __restrict__ loss_sum,
                 int* __restrict__ nflag) {
    counts[threadIdx.x] = 0u;
    if (threadIdx.x == 0) { loss_sum[0] = 0.f; nflag[0] = 0; }
}

// ---------------- numpy-pairwise sum of squares (fp32 input, for e_sq) --------
__global__ __launch_bounds__(256)
void sq_pairwise(const float* __restrict__ src, float* __restrict__ dst, int nrows) {
    int t = threadIdx.x;
    int row = blockIdx.x * 32 + (t >> 3);
    int j = t & 7;
    if (row >= nrows) return;
    const float* p = src + (size_t)row * C_DIM + j;
    float v = p[0];
    float r = __fmul_rn(v, v);
#pragma unroll
    for (int i = 1; i < 16; ++i) {
        float u = p[i * 8];
        r = __fadd_rn(r, __fmul_rn(u, u));
    }
    r = __fadd_rn(r, __shfl_xor(r, 1));
    r = __fadd_rn(r, __shfl_xor(r, 2));
    r = __fadd_rn(r, __shfl_xor(r, 4));
    if (j == 0) dst[row] = r;
}

// ---------------- same, from split-bf16 planes (for x_sq of flat) ----------
__global__ __launch_bounds__(256)
void sq_pairwise_bf(const ushort* __restrict__ Fh, const ushort* __restrict__ Fl,
                    float* __restrict__ dst, int nrows) {
    int t = threadIdx.x;
    int row = blockIdx.x * 32 + (t >> 3);
    int j = t & 7;
    if (row >= nrows) return;
    const ushort* ph = Fh + (size_t)row * C_DIM + j;
    const ushort* pl = Fl + (size_t)row * C_DIM + j;
    float v = bf2f(ph[0]) + bf2f(pl[0]);
    float r = __fmul_rn(v, v);
#pragma unroll
    for (int i = 1; i < 16; ++i) {
        float u = bf2f(ph[i * 8]) + bf2f(pl[i * 8]);
        r = __fadd_rn(r, __fmul_rn(u, u));
    }
    r = __fadd_rn(r, __shfl_xor(r, 1));
    r = __fadd_rn(r, __shfl_xor(r, 2));
    r = __fadd_rn(r, __shfl_xor(r, 4));
    if (j == 0) dst[row] = r;
}

// ---------------- split fp32 matrix into bf16 hi+lo ----------------
__global__ __launch_bounds__(256)
void split_hi_lo(const float* __restrict__ src, ushort* __restrict__ hi,
                 ushort* __restrict__ lo, int n4) {
    int e = blockIdx.x * 256 + threadIdx.x;
    if (e >= n4) return;
    float4 v = *(const float4*)&src[(size_t)e * 4];
    ushort h0 = f2bf(v.x), h1 = f2bf(v.y), h2 = f2bf(v.z), h3 = f2bf(v.w);
    ushort l0 = f2bf(v.x - bf2f(h0)), l1 = f2bf(v.y - bf2f(h1));
    ushort l2 = f2bf(v.z - bf2f(h2)), l3 = f2bf(v.w - bf2f(h3));
    ushort4 H; H.x = h0; H.y = h1; H.z = h2; H.w = h3;
    ushort4 L; L.x = l0; L.y = l1; L.z = l2; L.w = l3;
    *(ushort4*)&hi[(size_t)e * 4] = H;
    *(ushort4*)&lo[(size_t)e * 4] = L;
}

// ---------------- encoder: split-bf16 MFMA GEMM, 2-phase pipelined ----------
__global__ __launch_bounds__(256)
void enc_mfma(const float* __restrict__ h, const ushort* __restrict__ EWh,
              const ushort* __restrict__ EWl, const float* __restrict__ bias,
              ushort* __restrict__ Fh, ushort* __restrict__ Fl)
{
    constexpr int K = D_DIM, N = KC_DIM;
    __shared__ ushort Ahs[2][4096], Als[2][4096], Bhs[2][4096], Bls[2][4096];
    const int gid = blockIdx.x;                 // 1024 blocks
    const int f   = (gid & 7) * 128 + (gid >> 3);
    const int bx  = f & 3, by = f >> 2;         // 4 col-blocks, 256 row-blocks
    const int row0 = by * 128, col0 = bx * 128;
    const int tid  = threadIdx.x;
    const int lane = tid & 63, wave = tid >> 6;
    const int wm = wave >> 1, wn = wave & 1;

    f32x4 acc[4][4];
#pragma unroll
    for (int i = 0; i < 4; ++i)
#pragma unroll
        for (int j = 0; j < 4; ++j)
#pragma unroll
            for (int q = 0; q < 4; ++q) acc[i][j][q] = 0.f;

    const int fr = lane & 15, s4 = lane >> 4;
    const int arow = tid >> 3, ak8 = tid & 7;

    float4 hv[4];

#define ENC_LOAD_H(kt) do {                                                           \
    _Pragma("unroll")                                                                 \
    for (int q = 0; q < 4; ++q)                                                       \
        hv[q] = *(const float4*)&h[(size_t)(row0 + q * 32 + arow) * K + (kt) * 32 + ak8 * 4]; \
} while (0)

#define ENC_STAGE_B(p, kt) do {                                                       \
    _Pragma("unroll")                                                                 \
    for (int r = 0; r < 2; ++r) {                                                     \
        const int t2 = r * 256 + wave * 64 + lane;                                    \
        const int ro = t2 >> 2, sb = t2 & 3;                                          \
        const int base = (r * 256 + wave * 64) * 8;                                   \
        const size_t gb = (size_t)(col0 + ro) * K + (kt) * 32 + sb * 8;               \
        __builtin_amdgcn_global_load_lds(AS1(EWh + gb), AS3(&Bhs[p][base]), 16, 0, 0);\
        __builtin_amdgcn_global_load_lds(AS1(EWl + gb), AS3(&Bls[p][base]), 16, 0, 0);\
    }                                                                                 \
} while (0)

#define ENC_CONV_A(p) do {                                                            \
    _Pragma("unroll")                                                                 \
    for (int q = 0; q < 4; ++q) {                                                     \
        const int row = q * 32 + arow;                                                \
        ushort h0 = f2bf(hv[q].x), h1 = f2bf(hv[q].y);                                \
        ushort h2 = f2bf(hv[q].z), h3 = f2bf(hv[q].w);                                \
        ushort l0 = f2bf(hv[q].x - bf2f(h0)), l1 = f2bf(hv[q].y - bf2f(h1));          \
        ushort l2 = f2bf(hv[q].z - bf2f(h2)), l3 = f2bf(hv[q].w - bf2f(h3));          \
        ushort4 H; H.x = h0; H.y = h1; H.z = h2; H.w = h3;                            \
        ushort4 L; L.x = l0; L.y = l1; L.z = l2; L.w = l3;                            \
        *(ushort4*)&Ahs[p][row * 32 + ak8 * 4] = H;                                   \
        *(ushort4*)&Als[p][row * 32 + ak8 * 4] = L;                                   \
    }                                                                                 \
} while (0)

    // prologue: tile 0 -> buffer 0
    ENC_LOAD_H(0);
    ENC_STAGE_B(0, 0);
    ENC_CONV_A(0);
    __syncthreads();

    int cur = 0;
#pragma unroll 1
    for (int kt = 0; kt < K / 32 - 1; ++kt) {
        ENC_LOAD_H(kt + 1);                 // h loads in flight during compute
        ENC_STAGE_B(cur ^ 1, kt + 1);       // B DMA in flight during compute
        MFMA_COMPUTE(cur);
        ENC_CONV_A(cur ^ 1);                // waits only the h loads (in-order)
        asm volatile("s_waitcnt vmcnt(0)" ::: "memory");  // B landed (cheap now)
        __syncthreads();
        cur ^= 1;
    }
    MFMA_COMPUTE(cur);

#undef ENC_LOAD_H
#undef ENC_STAGE_B
#undef ENC_CONV_A

    // epilogue: flat value -> split bf16 planes
#pragma unroll
    for (int ni = 0; ni < 4; ++ni) {
        const int c = col0 + wn * 64 + ni * 16 + fr;
        const float bv = bias[c];
#pragma unroll
        for (int mi = 0; mi < 4; ++mi) {
            const int r = row0 + wm * 64 + mi * 16 + s4 * 4;
#pragma unroll
            for (int q = 0; q < 4; ++q) {
                float val = acc[mi][ni][q] + bv;
                ushort hi = f2bf(val);
                ushort lo = f2bf(val - bf2f(hi));
                size_t e = (size_t)(r + q) * N + c;
                Fh[e] = hi;
                Fl[e] = lo;
            }
        }
    }
}

// ---------------- dist on matrix cores: all-bf16, 2-phase pipelined ----------
__global__ __launch_bounds__(256)
void dist_mfma(const ushort* __restrict__ Fh, const ushort* __restrict__ Fl,
               const ushort* __restrict__ cbh, const ushort* __restrict__ cbl,
               const float* __restrict__ xsq, const float* __restrict__ esq,
               float* __restrict__ pmin, float* __restrict__ psec,
               int* __restrict__ pidx)
{
    constexpr int K = C_DIM;                    // 128
    __shared__ ushort Ahs[2][4096], Als[2][4096], Bhs[2][4096], Bls[2][4096];
    const int gid = blockIdx.x;                 // 4096 blocks
    const int f   = (gid & 7) * 512 + (gid >> 3);
    const int bx  = f & 3, by = f >> 2;         // 4 col-blocks, 1024 row-blocks
    const int row0 = by * 128, col0 = bx * 128;
    const int tid  = threadIdx.x;
    const int lane = tid & 63, wave = tid >> 6;
    const int wm = wave >> 1, wn = wave & 1;

    f32x4 acc[4][4];
#pragma unroll
    for (int i = 0; i < 4; ++i)
#pragma unroll
        for (int j = 0; j < 4; ++j)
#pragma unroll
            for (int q = 0; q < 4; ++q) acc[i][j][q] = 0.f;

    const int fr = lane & 15, s4 = lane >> 4;

#define DIST_STAGE(p, kt) do {                                                        \
    _Pragma("unroll")                                                                 \
    for (int r = 0; r < 2; ++r) {                                                     \
        const int t2 = r * 256 + wave * 64 + lane;                                    \
        const int ro = t2 >> 2, sb = t2 & 3;                                          \
        const int base = (r * 256 + wave * 64) * 8;                                   \
        const size_t ga = (size_t)(row0 + ro) * K + (kt) * 32 + sb * 8;               \
        const size_t gb = (size_t)(col0 + ro) * K + (kt) * 32 + sb * 8;               \
        __builtin_amdgcn_global_load_lds(AS1(Fh + ga),  AS3(&Ahs[p][base]), 16, 0, 0);\
        __builtin_amdgcn_global_load_lds(AS1(Fl + ga),  AS3(&Als[p][base]), 16, 0, 0);\
        __builtin_amdgcn_global_load_lds(AS1(cbh + gb), AS3(&Bhs[p][base]), 16, 0, 0);\
        __builtin_amdgcn_global_load_lds(AS1(cbl + gb), AS3(&Bls[p][base]), 16, 0, 0);\
    }                                                                                 \
} while (0)

    DIST_STAGE(0, 0);
    __syncthreads();
    int cur = 0;
#pragma unroll 1
    for (int kt = 0; kt < K / 32 - 1; ++kt) {
        DIST_STAGE(cur ^ 1, kt + 1);
        MFMA_COMPUTE(cur);
        asm volatile("s_waitcnt vmcnt(0)" ::: "memory");
        __syncthreads();
        cur ^= 1;
    }
    MFMA_COMPUTE(cur);
    __syncthreads();    // before reusing LDS as scratch

#undef DIST_STAGE

    // epilogue: dist + per-row (best, second, idx). LDS scratch aliases Ahs/Als
    float* bB = (float*)&Ahs[0][0];          // [128][2]
    float* sB = (float*)&Ahs[0][0] + 256;    // [128][2]
    int*   iB = (int*)&Als[0][0];            // [128][2]

    float es_v[4];
#pragma unroll
    for (int ni = 0; ni < 4; ++ni) es_v[ni] = esq[col0 + wn * 64 + ni * 16 + fr];

#pragma unroll
    for (int mi = 0; mi < 4; ++mi) {
#pragma unroll
        for (int q = 0; q < 4; ++q) {
            const int r = wm * 64 + mi * 16 + s4 * 4 + q;
            const float xs = xsq[row0 + r];
            float b = FLT_BIG, s = FLT_BIG; int bi = 0;
#pragma unroll
            for (int ni = 0; ni < 4; ++ni) {
                float d = (xs - 2.0f * acc[mi][ni][q]) + es_v[ni];
                int c = col0 + wn * 64 + ni * 16 + fr;
                if (d < b) { s = b; b = d; bi = c; }
                else       { s = fminf(s, d); }
            }
#pragma unroll
            for (int m = 1; m < 16; m <<= 1) {
                float b2 = __shfl_xor(b, m);
                float s2 = __shfl_xor(s, m);
                int   i2 = __shfl_xor(bi, m);
                if (b2 < b || (b2 == b && i2 < bi)) { s = fminf(b, s2); b = b2; bi = i2; }
                else                                { s = fminf(s, b2); }
            }
            if (fr == 0) { bB[r * 2 + wn] = b; sB[r * 2 + wn] = s; iB[r * 2 + wn] = bi; }
        }
    }
    __syncthreads();
    if (tid < 128) {
        float b0 = bB[tid * 2],     s0 = sB[tid * 2];     int i0 = iB[tid * 2];
        float b1 = bB[tid * 2 + 1], s1 = sB[tid * 2 + 1]; int i1 = iB[tid * 2 + 1];
        float b, s; int ix;
        if (b1 < b0) { b = b1; s = fminf(b0, s1); ix = i1; }
        else         { b = b0; s = fminf(s0, b1); ix = i0; }
        size_t o = (size_t)(row0 + tid) * 4 + bx;
        pmin[o] = b; psec[o] = s; pidx[o] = ix;
    }
}

// ---------------- merge 4 col-blocks -> idx + near-tie flags ----------------
__global__ __launch_bounds__(256)
void merge_flag(const float* __restrict__ pmin, const float* __restrict__ psec,
                const int* __restrict__ pidx, int* __restrict__ idx_int,
                float* __restrict__ idx_f, int* __restrict__ rowlist,
                int* __restrict__ nflag) {
    int row = blockIdx.x * 256 + threadIdx.x;
    size_t base = (size_t)row * 4;
    float b = pmin[base], sde = psec[base]; int ix = pidx[base];
#pragma unroll
    for (int nb = 1; nb < 4; ++nb) {
        float b2 = pmin[base + nb], s2 = psec[base + nb];
        if (b2 < b) { sde = fminf(b, s2); b = b2; ix = pidx[base + nb]; }
        else        { sde = fminf(sde, b2); }
    }
    idx_int[row] = ix;
    idx_f[row] = (float)ix;
    if (sde - b < GAP_EPS) {
        int p = atomicAdd(nflag, 1);
        rowlist[p] = row;
    }
}

// ---------------- exact recompute of near-tie rows (numpy-bit-exact) ----------
__global__ __launch_bounds__(256)
void refine_rows(const float* __restrict__ h, const float* __restrict__ enc_w,
                 const float* __restrict__ enc_b, const float* __restrict__ cb,
                 const float* __restrict__ esq, const int* __restrict__ rowlist,
                 const int* __restrict__ nflag_p, int* __restrict__ idx_int,
                 float* __restrict__ idx_f)
{
    __shared__ __align__(16) float x[C_DIM];
    __shared__ float xs_sh;
    __shared__ float rb[256];
    __shared__ int   ri[256];
    const int tid = threadIdx.x;
    const int nf = *nflag_p;
    for (int fi = blockIdx.x; fi < nf; fi += gridDim.x) {
        const int row = rowlist[fi];
        const int bt = row >> 2, seg = row & 3;
        if (tid < C_DIM) {
            const float* hp = h + (size_t)bt * D_DIM;
            const float* wp = enc_w + (size_t)(seg * C_DIM + tid) * D_DIM;
            float acc = 0.f, accC = 0.f;
            int fold = 96;   // 384/4
#pragma unroll 8
            for (int d = 0; d < D_DIM; d += 4) {
                float4 hv = *(const float4*)(hp + d);
                float4 wv = *(const float4*)(wp + d);
                accC = fmaf(hv.x, wv.x, accC);
                accC = fmaf(hv.y, wv.y, accC);
                accC = fmaf(hv.z, wv.z, accC);
                accC = fmaf(hv.w, wv.w, accC);
                if (--fold == 0) { acc = __fadd_rn(acc, accC); accC = 0.f; fold = 96; }
            }
            acc = __fadd_rn(acc, accC);   // K%384=128 remainder
            x[tid] = __fadd_rn(acc, enc_b[seg * C_DIM + tid]);
        }
        __syncthreads();
        if (tid == 0) {
            float rj[8];
#pragma unroll
            for (int j = 0; j < 8; ++j) rj[j] = __fmul_rn(x[j], x[j]);
            for (int i = 1; i < 16; ++i)
#pragma unroll
                for (int j = 0; j < 8; ++j)
                    rj[j] = __fadd_rn(rj[j], __fmul_rn(x[i * 8 + j], x[i * 8 + j]));
            float a01 = __fadd_rn(rj[0], rj[1]);
            float a23 = __fadd_rn(rj[2], rj[3]);
            float a45 = __fadd_rn(rj[4], rj[5]);
            float a67 = __fadd_rn(rj[6], rj[7]);
            xs_sh = __fadd_rn(__fadd_rn(a01, a23), __fadd_rn(a45, a67));
        }
        __syncthreads();
        const float xs = xs_sh;
        float best; int bi;
        {
            const int c0 = tid * 2;
            const float* e0 = cb + (size_t)c0 * C_DIM;
            float dot0 = 0.f, dot1 = 0.f;
#pragma unroll 4
            for (int c = 0; c < C_DIM; c += 4) {
                float4 xv  = *(const float4*)&x[c];
                float4 ev0 = *(const float4*)(e0 + c);
                float4 ev1 = *(const float4*)(e0 + C_DIM + c);
                dot0 = fmaf(xv.x, ev0.x, dot0); dot0 = fmaf(xv.y, ev0.y, dot0);
                dot0 = fmaf(xv.z, ev0.z, dot0); dot0 = fmaf(xv.w, ev0.w, dot0);
                dot1 = fmaf(xv.x, ev1.x, dot1); dot1 = fmaf(xv.y, ev1.y, dot1);
                dot1 = fmaf(xv.z, ev1.z, dot1); dot1 = fmaf(xv.w, ev1.w, dot1);
            }
            float d0 = __fadd_rn(__fsub_rn(xs, __fmul_rn(2.0f, dot0)), esq[c0]);
            float d1 = __fadd_rn(__fsub_rn(xs, __fmul_rn(2.0f, dot1)), esq[c0 + 1]);
            if (d1 < d0) { best = d1; bi = c0 + 1; } else { best = d0; bi = c0; }
        }
        rb[tid] = best; ri[tid] = bi;
        __syncthreads();
        for (int st = 128; st; st >>= 1) {
            if (tid < st) {
                float d2 = rb[tid + st]; int i2 = ri[tid + st];
                if (d2 < rb[tid] || (d2 == rb[tid] && i2 < ri[tid])) {
                    rb[tid] = d2; ri[tid] = i2;
                }
            }
            __syncthreads();
        }
        if (tid == 0) { idx_int[row] = ri[0]; idx_f[row] = (float)ri[0]; }
        __syncthreads();
    }
}

// ---------------- histogram over final indices ----------------
__global__ __launch_bounds__(256)
void histogram_kernel(const int* __restrict__ idx_int, unsigned* __restrict__ counts) {
    __shared__ unsigned hist[NCODES];
    int t = threadIdx.x;
    hist[t] = 0u; hist[t + 256] = 0u;
    __syncthreads();
    int row = blockIdx.x * 256 + t;
    atomicAdd(&hist[idx_int[row]], 1u);
    __syncthreads();
    if (hist[t]) atomicAdd(&counts[t], hist[t]);
    if (hist[t + 256]) atomicAdd(&counts[t + 256], hist[t + 256]);
}

// ---------------- fused: loss from Fh/Fl, then overwrite with quantized Q ----
__global__ __launch_bounds__(256)
void loss_and_q(ushort* __restrict__ Fh, ushort* __restrict__ Fl,
                const int* __restrict__ idx, const float* __restrict__ cb,
                const ushort* __restrict__ cbh, const ushort* __restrict__ cbl,
                float* __restrict__ loss_sum) {
    size_t e0 = ((size_t)blockIdx.x * 256 + threadIdx.x) * 8;
    int n = (int)(e0 >> 7);
    int c = (int)(e0 & 127);
    int k = idx[n];
    const float4* qp = (const float4*)(cb + (size_t)k * C_DIM + c);
    float4 q0 = qp[0], q1 = qp[1];
    ushort4 h0 = *(const ushort4*)&Fh[e0], h1 = *(const ushort4*)&Fh[e0 + 4];
    ushort4 l0 = *(const ushort4*)&Fl[e0], l1 = *(const ushort4*)&Fl[e0 + 4];
    float s = 0.f, d;
    d = q0.x - (bf2f(h0.x) + bf2f(l0.x)); s += d * d;
    d = q0.y - (bf2f(h0.y) + bf2f(l0.y)); s += d * d;
    d = q0.z - (bf2f(h0.z) + bf2f(l0.z)); s += d * d;
    d = q0.w - (bf2f(h0.w) + bf2f(l0.w)); s += d * d;
    d = q1.x - (bf2f(h1.x) + bf2f(l1.x)); s += d * d;
    d = q1.y - (bf2f(h1.y) + bf2f(l1.y)); s += d * d;
    d = q1.z - (bf2f(h1.z) + bf2f(l1.z)); s += d * d;
    d = q1.w - (bf2f(h1.w) + bf2f(l1.w)); s += d * d;

    // overwrite same bytes with gathered split-bf16 code row (Qh==Fh, Ql==Fl)
    uint4 vh = *(const uint4*)&cbh[(size_t)k * C_DIM + c];
    uint4 vl = *(const uint4*)&cbl[(size_t)k * C_DIM + c];
    *(uint4*)&Fh[e0] = vh;
    *(uint4*)&Fl[e0] = vl;

    __shared__ float redf[256];
    redf[threadIdx.x] = s;
    __syncthreads();
    for (int st = 128; st; st >>= 1) {
        if (threadIdx.x < st) redf[threadIdx.x] += redf[threadIdx.x + st];
        __syncthreads();
    }
    if (threadIdx.x == 0) atomicAdd(loss_sum, redf[0]);
}

// ---------------- decoder: split-bf16 MFMA GEMM, 2-phase pipelined ----------
__global__ __launch_bounds__(256)
void dec_gemm_bf16(const ushort* __restrict__ Qh, const ushort* __restrict__ Ql,
                   const ushort* __restrict__ Wh, const ushort* __restrict__ Wl,
                   const float* __restrict__ bias, float* __restrict__ C)
{
    constexpr int Kd = 512, Nd = 2048;
    __shared__ ushort Ahs[2][4096], Als[2][4096], Bhs[2][4096], Bls[2][4096];
    const int gid = blockIdx.x;                       // 4096 blocks
    const int f   = (gid & 7) * 512 + (gid >> 3);
    const int bx  = f & 15, by = f >> 4;
    const int tid  = threadIdx.x;
    const int lane = tid & 63, wave = tid >> 6;
    const int wm = wave >> 1, wn = wave & 1;
    const int row0 = by * 128, col0 = bx * 128;

    f32x4 acc[4][4];
#pragma unroll
    for (int i = 0; i < 4; ++i)
#pragma unroll
        for (int j = 0; j < 4; ++j)
#pragma unroll
            for (int q = 0; q < 4; ++q) acc[i][j][q] = 0.f;

    const int fr = lane & 15, s4 = lane >> 4;

#define DEC_STAGE(p, kt) do {                                                         \
    _Pragma("unroll")                                                                 \
    for (int r = 0; r < 2; ++r) {                                                     \
        const int t2 = r * 256 + wave * 64 + lane;                                    \
        const int ro = t2 >> 2, sb = t2 & 3;                                          \
        const int base = (r * 256 + wave * 64) * 8;                                   \
        const size_t ga = (size_t)(row0 + ro) * Kd + (kt) * 32 + sb * 8;              \
        const size_t gb = (size_t)(col0 + ro) * Kd + (kt) * 32 + sb * 8;              \
        __builtin_amdgcn_global_load_lds(AS1(Qh + ga), AS3(&Ahs[p][base]), 16, 0, 0); \
        __builtin_amdgcn_global_load_lds(AS1(Ql + ga), AS3(&Als[p][base]), 16, 0, 0); \
        __builtin_amdgcn_global_load_lds(AS1(Wh + gb), AS3(&Bhs[p][base]), 16, 0, 0); \
        __builtin_amdgcn_global_load_lds(AS1(Wl + gb), AS3(&Bls[p][base]), 16, 0, 0); \
    }                                                                                 \
} while (0)

    DEC_STAGE(0, 0);
    __syncthreads();
    int cur = 0;
#pragma unroll 1
    for (int kt = 0; kt < Kd / 32 - 1; ++kt) {
        DEC_STAGE(cur ^ 1, kt + 1);
        MFMA_COMPUTE(cur);
        asm volatile("s_waitcnt vmcnt(0)" ::: "memory");
        __syncthreads();
        cur ^= 1;
    }
    MFMA_COMPUTE(cur);

#undef DEC_STAGE

#pragma unroll
    for (int ni = 0; ni < 4; ++ni) {
        const int c = col0 + wn * 64 + ni * 16 + fr;
        const float bv = bias[c];
#pragma unroll
        for (int mi = 0; mi < 4; ++mi) {
            const int r = row0 + wm * 64 + mi * 16 + s4 * 4;
#pragma unroll
            for (int q = 0; q < 4; ++q)
                C[(size_t)(r + q) * Nd + c] = acc[mi][ni][q] + bv;
        }
    }
}

// ---------------- scalars ----------------
__global__ __launch_bounds__(512)
void finalize_scalars(const unsigned* __restrict__ counts,
                      const float* __restrict__ loss_sum, float* __restrict__ out5) {
    __shared__ float rent[512];
    __shared__ float ruse[512];
    int t = threadIdx.x;
    float c = (float)counts[t];
    float avg = c * (1.0f / (float)NROWS);
    rent[t] = avg * logf(avg + 1e-10f);
    ruse[t] = counts[t] > 0u ? 1.f : 0.f;
    __syncthreads();
    for (int st = 256; st; st >>= 1) {
        if (t < st) { rent[t] += rent[t + st]; ruse[t] += ruse[t + st]; }
        __syncthreads();
    }
    if (t == 0) {
        float H = -rent[0];
        float perp = expf(H);
        float cl = loss_sum[0] * (1.0f / (float)NELEM);
        out5[0] = cl + 0.25f * cl;
        out5[1] = cl;
        out5[2] = cl;
        out5[3] = perp;
        out5[4] = ruse[0] * (1.0f / (float)NCODES);
    }
}

extern "C" void kernel_launch(void* const* d_in, const int* in_sizes, int n_in,
                              void* d_out, int out_size, void* d_ws, size_t ws_size,
                              hipStream_t stream) {
    const float* h     = (const float*)d_in[0];
    const float* enc_w = (const float*)d_in[1];
    const float* enc_b = (const float*)d_in[2];
    const float* cb    = (const float*)d_in[3];
    const float* dec_w = (const float*)d_in[4];
    const float* dec_b = (const float*)d_in[5];
    float* out = (float*)d_out;

    float* ws = (float*)d_ws;
    ushort*   Fh       = (ushort*)ws;                // [0, 8388608)f
    ushort*   Fl       = (ushort*)(ws + 8388608);    // [8388608, 16777216)f
    float*    xsq      = ws + 16777216;              // 131072
    float*    pmin     = ws + 16908288;              // 524288
    float*    psec     = ws + 17432576;              // 524288
    int*      pidx     = (int*)(ws + 17956864);      // 524288
    int*      idx_int  = (int*)(ws + 18481152);      // 131072
    int*      rowlist  = (int*)(ws + 18612224);      // 131072
    float*    esq      = ws + 18743296;              // 512
    unsigned* counts   = (unsigned*)(ws + 18743808); // 512
    float*    loss_sum = ws + 18744320;              // 1
    int*      nflag    = (int*)(ws + 18744321);      // 1

    // overlays (hosts dead when used). cb split planes each = 32768 float-slots.
    ushort* EWh  = (ushort*)(ws + 16908288);         // over pmin  (pre-dist)
    ushort* EWl  = (ushort*)(ws + 17432576);         // over psec  (pre-dist)
    ushort* cbhd = (ushort*)(ws + 18612224);         // over rowlist[0..32767]   (pre-merge)
    ushort* cbld = (ushort*)(ws + 18644992);         // over rowlist[32768..65535]
    ushort* cbh  = (ushort*)(ws + 16777216);         // over xsq[0..32767]       (post-dist)
    ushort* cbl  = (ushort*)(ws + 16809984);         // over xsq[32768..65535]
    ushort* Wh   = (ushort*)(ws + 16908288);         // over pmin (post-merge)
    ushort* Wl   = (ushort*)(ws + 17432576);         // over psec (post-merge)

    float* msg_out = out;                     // 67108864
    float* idx_out = out + 67108864;          // 131072
    float* sc_out  = out + 67108864 + 131072; // 5

    zero_kernel<<<1, 512, 0, stream>>>(counts, loss_sum, nflag);
    sq_pairwise<<<NCODES / 32, 256, 0, stream>>>(cb, esq, NCODES);

    split_hi_lo<<<KC_DIM * D_DIM / 4 / 256, 256, 0, stream>>>(enc_w, EWh, EWl, KC_DIM * D_DIM / 4);
    split_hi_lo<<<NCODES * C_DIM / 4 / 256, 256, 0, stream>>>(cb, cbhd, cbld, NCODES * C_DIM / 4);

    // encoder on matrix cores (2-phase pipelined) -> split-bf16 flat planes
    enc_mfma<<<1024, 256, 0, stream>>>(h, EWh, EWl, enc_b, Fh, Fl);

    sq_pairwise_bf<<<NROWS / 32, 256, 0, stream>>>(Fh, Fl, xsq, NROWS);

    // distances on matrix cores (2-phase) + best/second/idx
    dist_mfma<<<4096, 256, 0, stream>>>(Fh, Fl, cbhd, cbld, xsq, esq, pmin, psec, pidx);

    merge_flag<<<NROWS / 256, 256, 0, stream>>>(pmin, psec, pidx, idx_int, idx_out,
                                                rowlist, nflag);

    refine_rows<<<2048, 256, 0, stream>>>(h, enc_w, enc_b, cb, esq, rowlist, nflag,
                                          idx_int, idx_out);

    histogram_kernel<<<NROWS / 256, 256, 0, stream>>>(idx_int, counts);

    // splits for decoder (xsq / pmin / psec dead now)
    split_hi_lo<<<NCODES * C_DIM / 4 / 256, 256, 0, stream>>>(cb, cbh, cbl, NCODES * C_DIM / 4);
    split_hi_lo<<<D_DIM * KC_DIM / 4 / 256, 256, 0, stream>>>(dec_w, Wh, Wl, D_DIM * KC_DIM / 4);

    // fused: loss from Fh/Fl, then overwrite in place with quantized Q
    loss_and_q<<<NELEM / (256 * 8), 256, 0, stream>>>(Fh, Fl, idx_int, cb, cbh, cbl, loss_sum);

    // decoder (2-phase pipelined); Qh==Fh, Ql==Fl after loss_and_q
    dec_gemm_bf16<<<4096, 256, 0, stream>>>(Fh, Fl, Wh, Wl, dec_b, msg_out);

    finalize_scalars<<<1, 512, 0, stream>>>(counts, loss_sum, sc_out);
}

// Round 17
// 850.440 us; speedup vs baseline: 1.1415x; 1.1415x over previous
//
#include <hip/hip_runtime.h>
#include <hip/hip_bf16.h>

// B=16, T=2048, D=2048, K(msg)=4, C=128, KC=512, CODEBOOK=512
#define M_BT      32768
#define KC_DIM    512
#define D_DIM     2048
#define C_DIM     128
#define NROWS     131072
#define NCODES    512
#define NELEM     16777216   // NROWS*C_DIM
#define GAP_EPS   6.0e-4f
#define FLT_BIG   3.4028235e38f

typedef __bf16 bf16x8 __attribute__((ext_vector_type(8)));
typedef float  f32x4  __attribute__((ext_vector_type(4)));

#define AS3(p) ((__attribute__((address_space(3))) void*)(p))
#define AS1(p) ((const __attribute__((address_space(1))) void*)(p))

static __device__ __forceinline__ ushort f2bf(float x) {
    unsigned u = __float_as_uint(x);
    unsigned r = (u + 0x7fffu + ((u >> 16) & 1u)) >> 16;
    return (ushort)r;
}
static __device__ __forceinline__ float bf2f(ushort u) {
    return __uint_as_float(((unsigned)u) << 16);
}

// shared MFMA compute macro: 16 frag-pairs x 3 products from subtile plane p
#define MFMA_COMPUTE(p) do {                                                          \
    bf16x8 ah[4], al[4], bh[4], bl[4];                                                \
    _Pragma("unroll")                                                                 \
    for (int mi = 0; mi < 4; ++mi) {                                                  \
        const int off = (wm * 64 + mi * 16 + fr) * 32 + s4 * 8;                       \
        ah[mi] = *(const bf16x8*)&Ahs[p][off];                                        \
        al[mi] = *(const bf16x8*)&Als[p][off];                                        \
    }                                                                                 \
    _Pragma("unroll")                                                                 \
    for (int ni = 0; ni < 4; ++ni) {                                                  \
        const int off = (wn * 64 + ni * 16 + fr) * 32 + s4 * 8;                       \
        bh[ni] = *(const bf16x8*)&Bhs[p][off];                                        \
        bl[ni] = *(const bf16x8*)&Bls[p][off];                                        \
    }                                                                                 \
    _Pragma("unroll")                                                                 \
    for (int mi = 0; mi < 4; ++mi)                                                    \
        _Pragma("unroll")                                                             \
        for (int ni = 0; ni < 4; ++ni) {                                              \
            acc[mi][ni] = __builtin_amdgcn_mfma_f32_16x16x32_bf16(ah[mi], bh[ni], acc[mi][ni], 0, 0, 0); \
            acc[mi][ni] = __builtin_amdgcn_mfma_f32_16x16x32_bf16(ah[mi], bl[ni], acc[mi][ni], 0, 0, 0); \
            acc[mi][ni] = __builtin_amdgcn_mfma_f32_16x16x32_bf16(al[mi], bh[ni], acc[mi][ni], 0, 0, 0); \
        }                                                                             \
} while (0)

// ---------------- zero counters ----------------
__global__ __launch_bounds__(512)
void zero_kernel(unsigned* __restrict__ counts, float* __restrict__ loss_sum,
                 int* __restrict__ nflag) {
    counts[threadIdx.x] = 0u;
    if (threadIdx.x == 0) { loss_sum[0] = 0.f; nflag[0] = 0; }
}

// ---------------- numpy-pairwise sum of squares (fp32 input, for e_sq) --------
__global__ __launch_bounds__(256)
void sq_pairwise(const float* __restrict__ src, float* __restrict__ dst, int nrows) {
    int t = threadIdx.x;
    int row = blockIdx.x * 32 + (t >> 3);
    int j = t & 7;
    if (row >= nrows) return;
    const float* p = src + (size_t)row * C_DIM + j;
    float v = p[0];
    float r = __fmul_rn(v, v);
#pragma unroll
    for (int i = 1; i < 16; ++i) {
        float u = p[i * 8];
        r = __fadd_rn(r, __fmul_rn(u, u));
    }
    r = __fadd_rn(r, __shfl_xor(r, 1));
    r = __fadd_rn(r, __shfl_xor(r, 2));
    r = __fadd_rn(r, __shfl_xor(r, 4));
    if (j == 0) dst[row] = r;
}

// ---------------- split fp32 matrix into bf16 hi+lo ----------------
__global__ __launch_bounds__(256)
void split_hi_lo(const float* __restrict__ src, ushort* __restrict__ hi,
                 ushort* __restrict__ lo, int n4) {
    int e = blockIdx.x * 256 + threadIdx.x;
    if (e >= n4) return;
    float4 v = *(const float4*)&src[(size_t)e * 4];
    ushort h0 = f2bf(v.x), h1 = f2bf(v.y), h2 = f2bf(v.z), h3 = f2bf(v.w);
    ushort l0 = f2bf(v.x - bf2f(h0)), l1 = f2bf(v.y - bf2f(h1));
    ushort l2 = f2bf(v.z - bf2f(h2)), l3 = f2bf(v.w - bf2f(h3));
    ushort4 H; H.x = h0; H.y = h1; H.z = h2; H.w = h3;
    ushort4 L; L.x = l0; L.y = l1; L.z = l2; L.w = l3;
    *(ushort4*)&hi[(size_t)e * 4] = H;
    *(ushort4*)&lo[(size_t)e * 4] = L;
}

// ---------------- encoder: split-bf16 MFMA GEMM, BK=64, fused xsq ----------
__global__ __launch_bounds__(256)
void enc_mfma(const float* __restrict__ h, const ushort* __restrict__ EWh,
              const ushort* __restrict__ EWl, const float* __restrict__ bias,
              ushort* __restrict__ Fh, ushort* __restrict__ Fl,
              float* __restrict__ xsq)
{
    constexpr int K = D_DIM, N = KC_DIM;
    __shared__ ushort Ahs[2][4096], Als[2][4096], Bhs[2][4096], Bls[2][4096];
    const int gid = blockIdx.x;                 // 1024 blocks
    const int f   = (gid & 7) * 128 + (gid >> 3);
    const int bx  = f & 3, by = f >> 2;         // 4 col-blocks, 256 row-blocks
    const int row0 = by * 128, col0 = bx * 128;
    const int tid  = threadIdx.x;
    const int lane = tid & 63, wave = tid >> 6;
    const int wm = wave >> 1, wn = wave & 1;

    f32x4 acc[4][4];
#pragma unroll
    for (int i = 0; i < 4; ++i)
#pragma unroll
        for (int j = 0; j < 4; ++j)
#pragma unroll
            for (int q = 0; q < 4; ++q) acc[i][j][q] = 0.f;

    const int fr = lane & 15, s4 = lane >> 4;
    const int arow = tid >> 3, ak8 = tid & 7;

#define ENC_STAGE(p, kt) do {                                                         \
    _Pragma("unroll")                                                                 \
    for (int r = 0; r < 2; ++r) {                                                     \
        const int t2 = r * 256 + wave * 64 + lane;                                    \
        const int ro = t2 >> 2, sb = t2 & 3;                                          \
        const int base = (r * 256 + wave * 64) * 8;                                   \
        const size_t gb = (size_t)(col0 + ro) * K + (kt) * 32 + sb * 8;               \
        __builtin_amdgcn_global_load_lds(AS1(EWh + gb), AS3(&Bhs[p][base]), 16, 0, 0);\
        __builtin_amdgcn_global_load_lds(AS1(EWl + gb), AS3(&Bls[p][base]), 16, 0, 0);\
    }                                                                                 \
    _Pragma("unroll")                                                                 \
    for (int q = 0; q < 4; ++q) {                                                     \
        const int row = q * 32 + arow;                                                \
        float4 v = *(const float4*)&h[(size_t)(row0 + row) * K + (kt) * 32 + ak8 * 4];\
        ushort h0 = f2bf(v.x), h1 = f2bf(v.y), h2 = f2bf(v.z), h3 = f2bf(v.w);        \
        ushort l0 = f2bf(v.x - bf2f(h0)), l1 = f2bf(v.y - bf2f(h1));                  \
        ushort l2 = f2bf(v.z - bf2f(h2)), l3 = f2bf(v.w - bf2f(h3));                  \
        ushort4 H; H.x = h0; H.y = h1; H.z = h2; H.w = h3;                            \
        ushort4 L; L.x = l0; L.y = l1; L.z = l2; L.w = l3;                            \
        *(ushort4*)&Ahs[p][row * 32 + ak8 * 4] = H;                                   \
        *(ushort4*)&Als[p][row * 32 + ak8 * 4] = L;                                   \
    }                                                                                 \
} while (0)

#pragma unroll 1
    for (int kt2 = 0; kt2 < K / 64; ++kt2) {    // 32 barrier periods
        ENC_STAGE(0, kt2 * 2);
        ENC_STAGE(1, kt2 * 2 + 1);
        __syncthreads();
        MFMA_COMPUTE(0);
        MFMA_COMPUTE(1);
        __syncthreads();
    }
#undef ENC_STAGE

    // epilogue: store split-bf16 flat + accumulate row sum-of-squares
    float ss[4][4];
#pragma unroll
    for (int mi = 0; mi < 4; ++mi)
#pragma unroll
        for (int q = 0; q < 4; ++q) ss[mi][q] = 0.f;

#pragma unroll
    for (int ni = 0; ni < 4; ++ni) {
        const int c = col0 + wn * 64 + ni * 16 + fr;
        const float bv = bias[c];
#pragma unroll
        for (int mi = 0; mi < 4; ++mi) {
            const int r = row0 + wm * 64 + mi * 16 + s4 * 4;
#pragma unroll
            for (int q = 0; q < 4; ++q) {
                float val = acc[mi][ni][q] + bv;
                ushort hi = f2bf(val);
                ushort lo = f2bf(val - bf2f(hi));
                size_t e = (size_t)(r + q) * N + c;
                Fh[e] = hi;
                Fl[e] = lo;
                ss[mi][q] += val * val;
            }
        }
    }
    // reduce ssq: 16 lanes (fr) per 16-group, then wn halves via LDS
    float* xpart = (float*)&Ahs[0][0];   // [128][2]
#pragma unroll
    for (int mi = 0; mi < 4; ++mi)
#pragma unroll
        for (int q = 0; q < 4; ++q) {
            float s = ss[mi][q];
            s += __shfl_xor(s, 1); s += __shfl_xor(s, 2);
            s += __shfl_xor(s, 4); s += __shfl_xor(s, 8);
            ss[mi][q] = s;
        }
    if (fr == 0) {
#pragma unroll
        for (int mi = 0; mi < 4; ++mi)
#pragma unroll
            for (int q = 0; q < 4; ++q)
                xpart[(wm * 64 + mi * 16 + s4 * 4 + q) * 2 + wn] = ss[mi][q];
    }
    __syncthreads();
    if (tid < 128)
        xsq[(size_t)(row0 + tid) * 4 + bx] = xpart[tid * 2] + xpart[tid * 2 + 1];
}

// ---------------- dist on matrix cores: all-bf16, BK=64 ----------
__global__ __launch_bounds__(256)
void dist_mfma(const ushort* __restrict__ Fh, const ushort* __restrict__ Fl,
               const ushort* __restrict__ cbh, const ushort* __restrict__ cbl,
               const float* __restrict__ xsq, const float* __restrict__ esq,
               float* __restrict__ pmin, float* __restrict__ psec,
               int* __restrict__ pidx)
{
    constexpr int K = C_DIM;                    // 128
    __shared__ ushort Ahs[2][4096], Als[2][4096], Bhs[2][4096], Bls[2][4096];
    const int gid = blockIdx.x;                 // 4096 blocks
    const int f   = (gid & 7) * 512 + (gid >> 3);
    const int bx  = f & 3, by = f >> 2;         // 4 col-blocks, 1024 row-blocks
    const int row0 = by * 128, col0 = bx * 128;
    const int tid  = threadIdx.x;
    const int lane = tid & 63, wave = tid >> 6;
    const int wm = wave >> 1, wn = wave & 1;

    f32x4 acc[4][4];
#pragma unroll
    for (int i = 0; i < 4; ++i)
#pragma unroll
        for (int j = 0; j < 4; ++j)
#pragma unroll
            for (int q = 0; q < 4; ++q) acc[i][j][q] = 0.f;

    const int fr = lane & 15, s4 = lane >> 4;

#define DIST_STAGE(p, kt) do {                                                        \
    _Pragma("unroll")                                                                 \
    for (int r = 0; r < 2; ++r) {                                                     \
        const int t2 = r * 256 + wave * 64 + lane;                                    \
        const int ro = t2 >> 2, sb = t2 & 3;                                          \
        const int base = (r * 256 + wave * 64) * 8;                                   \
        const size_t ga = (size_t)(row0 + ro) * K + (kt) * 32 + sb * 8;               \
        const size_t gb = (size_t)(col0 + ro) * K + (kt) * 32 + sb * 8;               \
        __builtin_amdgcn_global_load_lds(AS1(Fh + ga),  AS3(&Ahs[p][base]), 16, 0, 0);\
        __builtin_amdgcn_global_load_lds(AS1(Fl + ga),  AS3(&Als[p][base]), 16, 0, 0);\
        __builtin_amdgcn_global_load_lds(AS1(cbh + gb), AS3(&Bhs[p][base]), 16, 0, 0);\
        __builtin_amdgcn_global_load_lds(AS1(cbl + gb), AS3(&Bls[p][base]), 16, 0, 0);\
    }                                                                                 \
} while (0)

#pragma unroll 1
    for (int kt2 = 0; kt2 < K / 64; ++kt2) {    // 2 barrier periods
        DIST_STAGE(0, kt2 * 2);
        DIST_STAGE(1, kt2 * 2 + 1);
        __syncthreads();
        MFMA_COMPUTE(0);
        MFMA_COMPUTE(1);
        __syncthreads();
    }
#undef DIST_STAGE

    // epilogue: dist + per-row (best, second, idx). LDS scratch aliases Ahs/Als
    float* bB = (float*)&Ahs[0][0];          // [128][2]
    float* sB = (float*)&Ahs[0][0] + 256;    // [128][2]
    int*   iB = (int*)&Als[0][0];            // [128][2]

    float es_v[4];
#pragma unroll
    for (int ni = 0; ni < 4; ++ni) es_v[ni] = esq[col0 + wn * 64 + ni * 16 + fr];

#pragma unroll
    for (int mi = 0; mi < 4; ++mi) {
#pragma unroll
        for (int q = 0; q < 4; ++q) {
            const int r = wm * 64 + mi * 16 + s4 * 4 + q;
            const float xs = xsq[row0 + r];
            float b = FLT_BIG, s = FLT_BIG; int bi = 0;
#pragma unroll
            for (int ni = 0; ni < 4; ++ni) {
                float d = (xs - 2.0f * acc[mi][ni][q]) + es_v[ni];
                int c = col0 + wn * 64 + ni * 16 + fr;
                if (d < b) { s = b; b = d; bi = c; }
                else       { s = fminf(s, d); }
            }
#pragma unroll
            for (int m = 1; m < 16; m <<= 1) {
                float b2 = __shfl_xor(b, m);
                float s2 = __shfl_xor(s, m);
                int   i2 = __shfl_xor(bi, m);
                if (b2 < b || (b2 == b && i2 < bi)) { s = fminf(b, s2); b = b2; bi = i2; }
                else                                { s = fminf(s, b2); }
            }
            if (fr == 0) { bB[r * 2 + wn] = b; sB[r * 2 + wn] = s; iB[r * 2 + wn] = bi; }
        }
    }
    __syncthreads();
    if (tid < 128) {
        float b0 = bB[tid * 2],     s0 = sB[tid * 2];     int i0 = iB[tid * 2];
        float b1 = bB[tid * 2 + 1], s1 = sB[tid * 2 + 1]; int i1 = iB[tid * 2 + 1];
        float b, s; int ix;
        if (b1 < b0) { b = b1; s = fminf(b0, s1); ix = i1; }
        else         { b = b0; s = fminf(s0, b1); ix = i0; }
        size_t o = (size_t)(row0 + tid) * 4 + bx;
        pmin[o] = b; psec[o] = s; pidx[o] = ix;
    }
}

// ---------------- merge 4 col-blocks -> idx + near-tie flags ----------------
__global__ __launch_bounds__(256)
void merge_flag(const float* __restrict__ pmin, const float* __restrict__ psec,
                const int* __restrict__ pidx, int* __restrict__ idx_int,
                float* __restrict__ idx_f, int* __restrict__ rowlist,
                int* __restrict__ nflag) {
    int row = blockIdx.x * 256 + threadIdx.x;
    size_t base = (size_t)row * 4;
    float b = pmin[base], sde = psec[base]; int ix = pidx[base];
#pragma unroll
    for (int nb = 1; nb < 4; ++nb) {
        float b2 = pmin[base + nb], s2 = psec[base + nb];
        if (b2 < b) { sde = fminf(b, s2); b = b2; ix = pidx[base + nb]; }
        else        { sde = fminf(sde, b2); }
    }
    idx_int[row] = ix;
    idx_f[row] = (float)ix;
    if (sde - b < GAP_EPS) {
        int p = atomicAdd(nflag, 1);
        rowlist[p] = row;
    }
}

// ---------------- exact recompute of near-tie rows (numpy-bit-exact) ----------
__global__ __launch_bounds__(256)
void refine_rows(const float* __restrict__ h, const float* __restrict__ enc_w,
                 const float* __restrict__ enc_b, const float* __restrict__ cb,
                 const float* __restrict__ esq, const int* __restrict__ rowlist,
                 const int* __restrict__ nflag_p, int* __restrict__ idx_int,
                 float* __restrict__ idx_f)
{
    __shared__ __align__(16) float x[C_DIM];
    __shared__ float xs_sh;
    __shared__ float rb[256];
    __shared__ int   ri[256];
    const int tid = threadIdx.x;
    const int nf = *nflag_p;
    for (int fi = blockIdx.x; fi < nf; fi += gridDim.x) {
        const int row = rowlist[fi];
        const int bt = row >> 2, seg = row & 3;
        if (tid < C_DIM) {
            const float* hp = h + (size_t)bt * D_DIM;
            const float* wp = enc_w + (size_t)(seg * C_DIM + tid) * D_DIM;
            float acc = 0.f, accC = 0.f;
            int fold = 96;   // 384/4
#pragma unroll 8
            for (int d = 0; d < D_DIM; d += 4) {
                float4 hv = *(const float4*)(hp + d);
                float4 wv = *(const float4*)(wp + d);
                accC = fmaf(hv.x, wv.x, accC);
                accC = fmaf(hv.y, wv.y, accC);
                accC = fmaf(hv.z, wv.z, accC);
                accC = fmaf(hv.w, wv.w, accC);
                if (--fold == 0) { acc = __fadd_rn(acc, accC); accC = 0.f; fold = 96; }
            }
            acc = __fadd_rn(acc, accC);   // K%384=128 remainder
            x[tid] = __fadd_rn(acc, enc_b[seg * C_DIM + tid]);
        }
        __syncthreads();
        if (tid == 0) {
            float rj[8];
#pragma unroll
            for (int j = 0; j < 8; ++j) rj[j] = __fmul_rn(x[j], x[j]);
            for (int i = 1; i < 16; ++i)
#pragma unroll
                for (int j = 0; j < 8; ++j)
                    rj[j] = __fadd_rn(rj[j], __fmul_rn(x[i * 8 + j], x[i * 8 + j]));
            float a01 = __fadd_rn(rj[0], rj[1]);
            float a23 = __fadd_rn(rj[2], rj[3]);
            float a45 = __fadd_rn(rj[4], rj[5]);
            float a67 = __fadd_rn(rj[6], rj[7]);
            xs_sh = __fadd_rn(__fadd_rn(a01, a23), __fadd_rn(a45, a67));
        }
        __syncthreads();
        const float xs = xs_sh;
        float best; int bi;
        {
            const int c0 = tid * 2;
            const float* e0 = cb + (size_t)c0 * C_DIM;
            float dot0 = 0.f, dot1 = 0.f;
#pragma unroll 4
            for (int c = 0; c < C_DIM; c += 4) {
                float4 xv  = *(const float4*)&x[c];
                float4 ev0 = *(const float4*)(e0 + c);
                float4 ev1 = *(const float4*)(e0 + C_DIM + c);
                dot0 = fmaf(xv.x, ev0.x, dot0); dot0 = fmaf(xv.y, ev0.y, dot0);
                dot0 = fmaf(xv.z, ev0.z, dot0); dot0 = fmaf(xv.w, ev0.w, dot0);
                dot1 = fmaf(xv.x, ev1.x, dot1); dot1 = fmaf(xv.y, ev1.y, dot1);
                dot1 = fmaf(xv.z, ev1.z, dot1); dot1 = fmaf(xv.w, ev1.w, dot1);
            }
            float d0 = __fadd_rn(__fsub_rn(xs, __fmul_rn(2.0f, dot0)), esq[c0]);
            float d1 = __fadd_rn(__fsub_rn(xs, __fmul_rn(2.0f, dot1)), esq[c0 + 1]);
            if (d1 < d0) { best = d1; bi = c0 + 1; } else { best = d0; bi = c0; }
        }
        rb[tid] = best; ri[tid] = bi;
        __syncthreads();
        for (int st = 128; st; st >>= 1) {
            if (tid < st) {
                float d2 = rb[tid + st]; int i2 = ri[tid + st];
                if (d2 < rb[tid] || (d2 == rb[tid] && i2 < ri[tid])) {
                    rb[tid] = d2; ri[tid] = i2;
                }
            }
            __syncthreads();
        }
        if (tid == 0) { idx_int[row] = ri[0]; idx_f[row] = (float)ri[0]; }
        __syncthreads();
    }
}

// ---------------- histogram over final indices ----------------
__global__ __launch_bounds__(256)
void histogram_kernel(const int* __restrict__ idx_int, unsigned* __restrict__ counts) {
    __shared__ unsigned hist[NCODES];
    int t = threadIdx.x;
    hist[t] = 0u; hist[t + 256] = 0u;
    __syncthreads();
    int row = blockIdx.x * 256 + t;
    atomicAdd(&hist[idx_int[row]], 1u);
    __syncthreads();
    if (hist[t]) atomicAdd(&counts[t], hist[t]);
    if (hist[t + 256]) atomicAdd(&counts[t + 256], hist[t + 256]);
}

// ---------------- fused: loss from Fh/Fl, then overwrite with quantized Q ----
__global__ __launch_bounds__(256)
void loss_and_q(ushort* __restrict__ Fh, ushort* __restrict__ Fl,
                const int* __restrict__ idx, const float* __restrict__ cb,
                const ushort* __restrict__ cbh, const ushort* __restrict__ cbl,
                float* __restrict__ loss_sum) {
    size_t e0 = ((size_t)blockIdx.x * 256 + threadIdx.x) * 8;
    int n = (int)(e0 >> 7);
    int c = (int)(e0 & 127);
    int k = idx[n];
    const float4* qp = (const float4*)(cb + (size_t)k * C_DIM + c);
    float4 q0 = qp[0], q1 = qp[1];
    ushort4 h0 = *(const ushort4*)&Fh[e0], h1 = *(const ushort4*)&Fh[e0 + 4];
    ushort4 l0 = *(const ushort4*)&Fl[e0], l1 = *(const ushort4*)&Fl[e0 + 4];
    float s = 0.f, d;
    d = q0.x - (bf2f(h0.x) + bf2f(l0.x)); s += d * d;
    d = q0.y - (bf2f(h0.y) + bf2f(l0.y)); s += d * d;
    d = q0.z - (bf2f(h0.z) + bf2f(l0.z)); s += d * d;
    d = q0.w - (bf2f(h0.w) + bf2f(l0.w)); s += d * d;
    d = q1.x - (bf2f(h1.x) + bf2f(l1.x)); s += d * d;
    d = q1.y - (bf2f(h1.y) + bf2f(l1.y)); s += d * d;
    d = q1.z - (bf2f(h1.z) + bf2f(l1.z)); s += d * d;
    d = q1.w - (bf2f(h1.w) + bf2f(l1.w)); s += d * d;

    // overwrite same bytes with gathered split-bf16 code row (Qh==Fh, Ql==Fl)
    uint4 vh = *(const uint4*)&cbh[(size_t)k * C_DIM + c];
    uint4 vl = *(const uint4*)&cbl[(size_t)k * C_DIM + c];
    *(uint4*)&Fh[e0] = vh;
    *(uint4*)&Fl[e0] = vl;

    __shared__ float redf[256];
    redf[threadIdx.x] = s;
    __syncthreads();
    for (int st = 128; st; st >>= 1) {
        if (threadIdx.x < st) redf[threadIdx.x] += redf[threadIdx.x + st];
        __syncthreads();
    }
    if (threadIdx.x == 0) atomicAdd(loss_sum, redf[0]);
}

// ---------------- decoder: split-bf16 MFMA GEMM, BK=64 ----------
__global__ __launch_bounds__(256)
void dec_gemm_bf16(const ushort* __restrict__ Qh, const ushort* __restrict__ Ql,
                   const ushort* __restrict__ Wh, const ushort* __restrict__ Wl,
                   const float* __restrict__ bias, float* __restrict__ C)
{
    constexpr int Kd = 512, Nd = 2048;
    __shared__ ushort Ahs[2][4096], Als[2][4096], Bhs[2][4096], Bls[2][4096];
    const int gid = blockIdx.x;                       // 4096 blocks
    const int f   = (gid & 7) * 512 + (gid >> 3);
    const int bx  = f & 15, by = f >> 4;
    const int tid  = threadIdx.x;
    const int lane = tid & 63, wave = tid >> 6;
    const int wm = wave >> 1, wn = wave & 1;
    const int row0 = by * 128, col0 = bx * 128;

    f32x4 acc[4][4];
#pragma unroll
    for (int i = 0; i < 4; ++i)
#pragma unroll
        for (int j = 0; j < 4; ++j)
#pragma unroll
            for (int q = 0; q < 4; ++q) acc[i][j][q] = 0.f;

    const int fr = lane & 15, s4 = lane >> 4;

#define DEC_STAGE(p, kt) do {                                                         \
    _Pragma("unroll")                                                                 \
    for (int r = 0; r < 2; ++r) {                                                     \
        const int t2 = r * 256 + wave * 64 + lane;                                    \
        const int ro = t2 >> 2, sb = t2 & 3;                                          \
        const int base = (r * 256 + wave * 64) * 8;                                   \
        const size_t ga = (size_t)(row0 + ro) * Kd + (kt) * 32 + sb * 8;              \
        const size_t gb = (size_t)(col0 + ro) * Kd + (kt) * 32 + sb * 8;              \
        __builtin_amdgcn_global_load_lds(AS1(Qh + ga), AS3(&Ahs[p][base]), 16, 0, 0); \
        __builtin_amdgcn_global_load_lds(AS1(Ql + ga), AS3(&Als[p][base]), 16, 0, 0); \
        __builtin_amdgcn_global_load_lds(AS1(Wh + gb), AS3(&Bhs[p][base]), 16, 0, 0); \
        __builtin_amdgcn_global_load_lds(AS1(Wl + gb), AS3(&Bls[p][base]), 16, 0, 0); \
    }                                                                                 \
} while (0)

#pragma unroll 1
    for (int kt2 = 0; kt2 < Kd / 64; ++kt2) {   // 8 barrier periods
        DEC_STAGE(0, kt2 * 2);
        DEC_STAGE(1, kt2 * 2 + 1);
        __syncthreads();
        MFMA_COMPUTE(0);
        MFMA_COMPUTE(1);
        __syncthreads();
    }
#undef DEC_STAGE

#pragma unroll
    for (int ni = 0; ni < 4; ++ni) {
        const int c = col0 + wn * 64 + ni * 16 + fr;
        const float bv = bias[c];
#pragma unroll
        for (int mi = 0; mi < 4; ++mi) {
            const int r = row0 + wm * 64 + mi * 16 + s4 * 4;
#pragma unroll
            for (int q = 0; q < 4; ++q)
                C[(size_t)(r + q) * Nd + c] = acc[mi][ni][q] + bv;
        }
    }
}

// ---------------- scalars ----------------
__global__ __launch_bounds__(512)
void finalize_scalars(const unsigned* __restrict__ counts,
                      const float* __restrict__ loss_sum, float* __restrict__ out5) {
    __shared__ float rent[512];
    __shared__ float ruse[512];
    int t = threadIdx.x;
    float c = (float)counts[t];
    float avg = c * (1.0f / (float)NROWS);
    rent[t] = avg * logf(avg + 1e-10f);
    ruse[t] = counts[t] > 0u ? 1.f : 0.f;
    __syncthreads();
    for (int st = 256; st; st >>= 1) {
        if (t < st) { rent[t] += rent[t + st]; ruse[t] += ruse[t + st]; }
        __syncthreads();
    }
    if (t == 0) {
        float H = -rent[0];
        float perp = expf(H);
        float cl = loss_sum[0] * (1.0f / (float)NELEM);
        out5[0] = cl + 0.25f * cl;
        out5[1] = cl;
        out5[2] = cl;
        out5[3] = perp;
        out5[4] = ruse[0] * (1.0f / (float)NCODES);
    }
}

extern "C" void kernel_launch(void* const* d_in, const int* in_sizes, int n_in,
                              void* d_out, int out_size, void* d_ws, size_t ws_size,
                              hipStream_t stream) {
    const float* h     = (const float*)d_in[0];
    const float* enc_w = (const float*)d_in[1];
    const float* enc_b = (const float*)d_in[2];
    const float* cb    = (const float*)d_in[3];
    const float* dec_w = (const float*)d_in[4];
    const float* dec_b = (const float*)d_in[5];
    float* out = (float*)d_out;

    float* ws = (float*)d_ws;
    ushort*   Fh       = (ushort*)ws;                // [0, 8388608)f
    ushort*   Fl       = (ushort*)(ws + 8388608);    // [8388608, 16777216)f
    float*    xsq      = ws + 16777216;              // 131072
    float*    pmin     = ws + 16908288;              // 524288
    float*    psec     = ws + 17432576;              // 524288
    int*      pidx     = (int*)(ws + 17956864);      // 524288
    int*      idx_int  = (int*)(ws + 18481152);      // 131072
    int*      rowlist  = (int*)(ws + 18612224);      // 131072
    float*    esq      = ws + 18743296;              // 512
    unsigned* counts   = (unsigned*)(ws + 18743808); // 512
    float*    loss_sum = ws + 18744320;              // 1
    int*      nflag    = (int*)(ws + 18744321);      // 1

    // overlays (hosts dead when used). cb split planes each = 32768 float-slots.
    ushort* EWh  = (ushort*)(ws + 16908288);         // over pmin  (pre-dist)
    ushort* EWl  = (ushort*)(ws + 17432576);         // over psec  (pre-dist)
    ushort* cbhd = (ushort*)(ws + 18612224);         // over rowlist[0..32767]   (pre-merge)
    ushort* cbld = (ushort*)(ws + 18644992);         // over rowlist[32768..65535]
    ushort* cbh  = (ushort*)(ws + 16777216);         // over xsq[0..32767]       (post-dist)
    ushort* cbl  = (ushort*)(ws + 16809984);         // over xsq[32768..65535]
    ushort* Wh   = (ushort*)(ws + 16908288);         // over pmin (post-merge)
    ushort* Wl   = (ushort*)(ws + 17432576);         // over psec (post-merge)

    float* msg_out = out;                     // 67108864
    float* idx_out = out + 67108864;          // 131072
    float* sc_out  = out + 67108864 + 131072; // 5

    zero_kernel<<<1, 512, 0, stream>>>(counts, loss_sum, nflag);
    sq_pairwise<<<NCODES / 32, 256, 0, stream>>>(cb, esq, NCODES);

    split_hi_lo<<<KC_DIM * D_DIM / 4 / 256, 256, 0, stream>>>(enc_w, EWh, EWl, KC_DIM * D_DIM / 4);
    split_hi_lo<<<NCODES * C_DIM / 4 / 256, 256, 0, stream>>>(cb, cbhd, cbld, NCODES * C_DIM / 4);

    // encoder on matrix cores (BK=64) -> split-bf16 flat planes + fused xsq
    enc_mfma<<<1024, 256, 0, stream>>>(h, EWh, EWl, enc_b, Fh, Fl, xsq);

    // distances on matrix cores (BK=64) + best/second/idx
    dist_mfma<<<4096, 256, 0, stream>>>(Fh, Fl, cbhd, cbld, xsq, esq, pmin, psec, pidx);

    merge_flag<<<NROWS / 256, 256, 0, stream>>>(pmin, psec, pidx, idx_int, idx_out,
                                                rowlist, nflag);

    refine_rows<<<2048, 256, 0, stream>>>(h, enc_w, enc_b, cb, esq, rowlist, nflag,
                                          idx_int, idx_out);

    histogram_kernel<<<NROWS / 256, 256, 0, stream>>>(idx_int, counts);

    // splits for decoder (xsq / pmin / psec dead now)
    split_hi_lo<<<NCODES * C_DIM / 4 / 256, 256, 0, stream>>>(cb, cbh, cbl, NCODES * C_DIM / 4);
    split_hi_lo<<<D_DIM * KC_DIM / 4 / 256, 256, 0, stream>>>(dec_w, Wh, Wl, D_DIM * KC_DIM / 4);

    // fused: loss from Fh/Fl, then overwrite in place with quantized Q
    loss_and_q<<<NELEM / (256 * 8), 256, 0, stream>>>(Fh, Fl, idx_int, cb, cbh, cbl, loss_sum);

    // decoder (BK=64); Qh==Fh, Ql==Fl after loss_and_q
    dec_gemm_bf16<<<4096, 256, 0, stream>>>(Fh, Fl, Wh, Wl, dec_b, msg_out);

    finalize_scalars<<<1, 512, 0, stream>>>(counts, loss_sum, sc_out);
}

// Round 18
// 775.554 us; speedup vs baseline: 1.2517x; 1.0966x over previous
//
#include <hip/hip_runtime.h>
#include <hip/hip_bf16.h>

// B=16, T=2048, D=2048, K(msg)=4, C=128, KC=512, CODEBOOK=512
#define M_BT      32768
#define KC_DIM    512
#define D_DIM     2048
#define C_DIM     128
#define NROWS     131072
#define NCODES    512
#define NELEM     16777216   // NROWS*C_DIM
#define GAP_EPS   6.0e-4f
#define FLT_BIG   3.4028235e38f

typedef __bf16 bf16x8 __attribute__((ext_vector_type(8)));
typedef float  f32x4  __attribute__((ext_vector_type(4)));

#define AS3(p) ((__attribute__((address_space(3))) void*)(p))
#define AS1(p) ((const __attribute__((address_space(1))) void*)(p))

static __device__ __forceinline__ ushort f2bf(float x) {
    __bf16 b = (__bf16)x;
    return __builtin_bit_cast(ushort, b);
}
static __device__ __forceinline__ float bf2f(ushort u) {
    return __uint_as_float(((unsigned)u) << 16);
}
static __device__ __forceinline__ void split1(float x, ushort& hi, ushort& lo) {
    __bf16 b = (__bf16)x;
    hi = __builtin_bit_cast(ushort, b);
    lo = __builtin_bit_cast(ushort, (__bf16)(x - (float)b));
}

// 3-product MFMA from subtile plane p (enc/dist)
#define MFMA_COMPUTE(p) do {                                                          \
    bf16x8 ah[4], al[4], bh[4], bl[4];                                                \
    _Pragma("unroll")                                                                 \
    for (int mi = 0; mi < 4; ++mi) {                                                  \
        const int off = (wm * 64 + mi * 16 + fr) * 32 + s4 * 8;                       \
        ah[mi] = *(const bf16x8*)&Ahs[p][off];                                        \
        al[mi] = *(const bf16x8*)&Als[p][off];                                        \
    }                                                                                 \
    _Pragma("unroll")                                                                 \
    for (int ni = 0; ni < 4; ++ni) {                                                  \
        const int off = (wn * 64 + ni * 16 + fr) * 32 + s4 * 8;                       \
        bh[ni] = *(const bf16x8*)&Bhs[p][off];                                        \
        bl[ni] = *(const bf16x8*)&Bls[p][off];                                        \
    }                                                                                 \
    _Pragma("unroll")                                                                 \
    for (int mi = 0; mi < 4; ++mi)                                                    \
        _Pragma("unroll")                                                             \
        for (int ni = 0; ni < 4; ++ni) {                                              \
            acc[mi][ni] = __builtin_amdgcn_mfma_f32_16x16x32_bf16(ah[mi], bh[ni], acc[mi][ni], 0, 0, 0); \
            acc[mi][ni] = __builtin_amdgcn_mfma_f32_16x16x32_bf16(ah[mi], bl[ni], acc[mi][ni], 0, 0, 0); \
            acc[mi][ni] = __builtin_amdgcn_mfma_f32_16x16x32_bf16(al[mi], bh[ni], acc[mi][ni], 0, 0, 0); \
        }                                                                             \
} while (0)

// 2-product MFMA (decoder: Qh x (Wh + Wl))
#define MFMA_COMPUTE2(p) do {                                                         \
    bf16x8 ah[4], bh[4], bl[4];                                                       \
    _Pragma("unroll")                                                                 \
    for (int mi = 0; mi < 4; ++mi) {                                                  \
        const int off = (wm * 64 + mi * 16 + fr) * 32 + s4 * 8;                       \
        ah[mi] = *(const bf16x8*)&Ahs[p][off];                                        \
    }                                                                                 \
    _Pragma("unroll")                                                                 \
    for (int ni = 0; ni < 4; ++ni) {                                                  \
        const int off = (wn * 64 + ni * 16 + fr) * 32 + s4 * 8;                       \
        bh[ni] = *(const bf16x8*)&Bhs[p][off];                                        \
        bl[ni] = *(const bf16x8*)&Bls[p][off];                                        \
    }                                                                                 \
    _Pragma("unroll")                                                                 \
    for (int mi = 0; mi < 4; ++mi)                                                    \
        _Pragma("unroll")                                                             \
        for (int ni = 0; ni < 4; ++ni) {                                              \
            acc[mi][ni] = __builtin_amdgcn_mfma_f32_16x16x32_bf16(ah[mi], bh[ni], acc[mi][ni], 0, 0, 0); \
            acc[mi][ni] = __builtin_amdgcn_mfma_f32_16x16x32_bf16(ah[mi], bl[ni], acc[mi][ni], 0, 0, 0); \
        }                                                                             \
} while (0)

// ---------------- zero counters ----------------
__global__ __launch_bounds__(512)
void zero_kernel(unsigned* __restrict__ counts, float* __restrict__ loss_sum,
                 int* __restrict__ nflag) {
    counts[threadIdx.x] = 0u;
    if (threadIdx.x == 0) { loss_sum[0] = 0.f; nflag[0] = 0; }
}

// ---------------- numpy-pairwise sum of squares (fp32 input, for e_sq) --------
__global__ __launch_bounds__(256)
void sq_pairwise(const float* __restrict__ src, float* __restrict__ dst, int nrows) {
    int t = threadIdx.x;
    int row = blockIdx.x * 32 + (t >> 3);
    int j = t & 7;
    if (row >= nrows) return;
    const float* p = src + (size_t)row * C_DIM + j;
    float v = p[0];
    float r = __fmul_rn(v, v);
#pragma unroll
    for (int i = 1; i < 16; ++i) {
        float u = p[i * 8];
        r = __fadd_rn(r, __fmul_rn(u, u));
    }
    r = __fadd_rn(r, __shfl_xor(r, 1));
    r = __fadd_rn(r, __shfl_xor(r, 2));
    r = __fadd_rn(r, __shfl_xor(r, 4));
    if (j == 0) dst[row] = r;
}

// ---------------- split fp32 matrix into bf16 hi+lo ----------------
__global__ __launch_bounds__(256)
void split_hi_lo(const float* __restrict__ src, ushort* __restrict__ hi,
                 ushort* __restrict__ lo, int n4) {
    int e = blockIdx.x * 256 + threadIdx.x;
    if (e >= n4) return;
    float4 v = *(const float4*)&src[(size_t)e * 4];
    ushort4 H, L;
    split1(v.x, H.x, L.x); split1(v.y, H.y, L.y);
    split1(v.z, H.z, L.z); split1(v.w, H.w, L.w);
    *(ushort4*)&hi[(size_t)e * 4] = H;
    *(ushort4*)&lo[(size_t)e * 4] = L;
}

// ---------------- split fp32 matrix into bf16 hi only ----------------
__global__ __launch_bounds__(256)
void split_hi(const float* __restrict__ src, ushort* __restrict__ hi, int n4) {
    int e = blockIdx.x * 256 + threadIdx.x;
    if (e >= n4) return;
    float4 v = *(const float4*)&src[(size_t)e * 4];
    ushort4 H;
    H.x = f2bf(v.x); H.y = f2bf(v.y); H.z = f2bf(v.z); H.w = f2bf(v.w);
    *(ushort4*)&hi[(size_t)e * 4] = H;
}

// ---------------- encoder: split-bf16 MFMA GEMM, BK=64, fused xsq ----------
__global__ __launch_bounds__(256)
void enc_mfma(const float* __restrict__ h, const ushort* __restrict__ EWh,
              const ushort* __restrict__ EWl, const float* __restrict__ bias,
              ushort* __restrict__ Fh, ushort* __restrict__ Fl,
              float* __restrict__ xsq)
{
    constexpr int K = D_DIM, N = KC_DIM;
    __shared__ ushort Ahs[2][4096], Als[2][4096], Bhs[2][4096], Bls[2][4096];
    const int gid = blockIdx.x;                 // 1024 blocks
    const int f   = (gid & 7) * 128 + (gid >> 3);
    const int bx  = f & 3, by = f >> 2;         // 4 col-blocks, 256 row-blocks
    const int row0 = by * 128, col0 = bx * 128;
    const int tid  = threadIdx.x;
    const int lane = tid & 63, wave = tid >> 6;
    const int wm = wave >> 1, wn = wave & 1;

    f32x4 acc[4][4];
#pragma unroll
    for (int i = 0; i < 4; ++i)
#pragma unroll
        for (int j = 0; j < 4; ++j)
#pragma unroll
            for (int q = 0; q < 4; ++q) acc[i][j][q] = 0.f;

    const int fr = lane & 15, s4 = lane >> 4;
    const int arow = tid >> 3, ak8 = tid & 7;

#define ENC_STAGE(p, kt) do {                                                         \
    _Pragma("unroll")                                                                 \
    for (int r = 0; r < 2; ++r) {                                                     \
        const int t2 = r * 256 + wave * 64 + lane;                                    \
        const int ro = t2 >> 2, sb = t2 & 3;                                          \
        const int base = (r * 256 + wave * 64) * 8;                                   \
        const size_t gb = (size_t)(col0 + ro) * K + (kt) * 32 + sb * 8;               \
        __builtin_amdgcn_global_load_lds(AS1(EWh + gb), AS3(&Bhs[p][base]), 16, 0, 0);\
        __builtin_amdgcn_global_load_lds(AS1(EWl + gb), AS3(&Bls[p][base]), 16, 0, 0);\
    }                                                                                 \
    _Pragma("unroll")                                                                 \
    for (int q = 0; q < 4; ++q) {                                                     \
        const int row = q * 32 + arow;                                                \
        float4 v = *(const float4*)&h[(size_t)(row0 + row) * K + (kt) * 32 + ak8 * 4];\
        ushort4 H, L;                                                                 \
        split1(v.x, H.x, L.x); split1(v.y, H.y, L.y);                                 \
        split1(v.z, H.z, L.z); split1(v.w, H.w, L.w);                                 \
        *(ushort4*)&Ahs[p][row * 32 + ak8 * 4] = H;                                   \
        *(ushort4*)&Als[p][row * 32 + ak8 * 4] = L;                                   \
    }                                                                                 \
} while (0)

#pragma unroll 1
    for (int kt2 = 0; kt2 < K / 64; ++kt2) {    // 32 barrier periods
        ENC_STAGE(0, kt2 * 2);
        ENC_STAGE(1, kt2 * 2 + 1);
        __syncthreads();
        MFMA_COMPUTE(0);
        MFMA_COMPUTE(1);
        __syncthreads();
    }
#undef ENC_STAGE

    // epilogue: store split-bf16 flat + accumulate row sum-of-squares
    float ss[4][4];
#pragma unroll
    for (int mi = 0; mi < 4; ++mi)
#pragma unroll
        for (int q = 0; q < 4; ++q) ss[mi][q] = 0.f;

#pragma unroll
    for (int ni = 0; ni < 4; ++ni) {
        const int c = col0 + wn * 64 + ni * 16 + fr;
        const float bv = bias[c];
#pragma unroll
        for (int mi = 0; mi < 4; ++mi) {
            const int r = row0 + wm * 64 + mi * 16 + s4 * 4;
#pragma unroll
            for (int q = 0; q < 4; ++q) {
                float val = acc[mi][ni][q] + bv;
                ushort hi, lo;
                split1(val, hi, lo);
                size_t e = (size_t)(r + q) * N + c;
                Fh[e] = hi;
                Fl[e] = lo;
                ss[mi][q] += val * val;
            }
        }
    }
    // reduce ssq: 16 lanes (fr) per 16-group, then wn halves via LDS
    float* xpart = (float*)&Ahs[0][0];   // [128][2]
#pragma unroll
    for (int mi = 0; mi < 4; ++mi)
#pragma unroll
        for (int q = 0; q < 4; ++q) {
            float s = ss[mi][q];
            s += __shfl_xor(s, 1); s += __shfl_xor(s, 2);
            s += __shfl_xor(s, 4); s += __shfl_xor(s, 8);
            ss[mi][q] = s;
        }
    if (fr == 0) {
#pragma unroll
        for (int mi = 0; mi < 4; ++mi)
#pragma unroll
            for (int q = 0; q < 4; ++q)
                xpart[(wm * 64 + mi * 16 + s4 * 4 + q) * 2 + wn] = ss[mi][q];
    }
    __syncthreads();
    if (tid < 128)
        xsq[(size_t)(row0 + tid) * 4 + bx] = xpart[tid * 2] + xpart[tid * 2 + 1];
}

// ---------------- dist on matrix cores: all-bf16, BK=64 ----------
__global__ __launch_bounds__(256)
void dist_mfma(const ushort* __restrict__ Fh, const ushort* __restrict__ Fl,
               const ushort* __restrict__ cbh, const ushort* __restrict__ cbl,
               const float* __restrict__ xsq, const float* __restrict__ esq,
               float* __restrict__ pmin, float* __restrict__ psec,
               int* __restrict__ pidx)
{
    constexpr int K = C_DIM;                    // 128
    __shared__ ushort Ahs[2][4096], Als[2][4096], Bhs[2][4096], Bls[2][4096];
    const int gid = blockIdx.x;                 // 4096 blocks
    const int f   = (gid & 7) * 512 + (gid >> 3);
    const int bx  = f & 3, by = f >> 2;         // 4 col-blocks, 1024 row-blocks
    const int row0 = by * 128, col0 = bx * 128;
    const int tid  = threadIdx.x;
    const int lane = tid & 63, wave = tid >> 6;
    const int wm = wave >> 1, wn = wave & 1;

    f32x4 acc[4][4];
#pragma unroll
    for (int i = 0; i < 4; ++i)
#pragma unroll
        for (int j = 0; j < 4; ++j)
#pragma unroll
            for (int q = 0; q < 4; ++q) acc[i][j][q] = 0.f;

    const int fr = lane & 15, s4 = lane >> 4;

#define DIST_STAGE(p, kt) do {                                                        \
    _Pragma("unroll")                                                                 \
    for (int r = 0; r < 2; ++r) {                                                     \
        const int t2 = r * 256 + wave * 64 + lane;                                    \
        const int ro = t2 >> 2, sb = t2 & 3;                                          \
        const int base = (r * 256 + wave * 64) * 8;                                   \
        const size_t ga = (size_t)(row0 + ro) * K + (kt) * 32 + sb * 8;               \
        const size_t gb = (size_t)(col0 + ro) * K + (kt) * 32 + sb * 8;               \
        __builtin_amdgcn_global_load_lds(AS1(Fh + ga),  AS3(&Ahs[p][base]), 16, 0, 0);\
        __builtin_amdgcn_global_load_lds(AS1(Fl + ga),  AS3(&Als[p][base]), 16, 0, 0);\
        __builtin_amdgcn_global_load_lds(AS1(cbh + gb), AS3(&Bhs[p][base]), 16, 0, 0);\
        __builtin_amdgcn_global_load_lds(AS1(cbl + gb), AS3(&Bls[p][base]), 16, 0, 0);\
    }                                                                                 \
} while (0)

#pragma unroll 1
    for (int kt2 = 0; kt2 < K / 64; ++kt2) {    // 2 barrier periods
        DIST_STAGE(0, kt2 * 2);
        DIST_STAGE(1, kt2 * 2 + 1);
        __syncthreads();
        MFMA_COMPUTE(0);
        MFMA_COMPUTE(1);
        __syncthreads();
    }
#undef DIST_STAGE

    // epilogue: dist + per-row (best, second, idx). LDS scratch aliases Ahs/Als
    float* bB = (float*)&Ahs[0][0];          // [128][2]
    float* sB = (float*)&Ahs[0][0] + 256;    // [128][2]
    int*   iB = (int*)&Als[0][0];            // [128][2]

    float es_v[4];
#pragma unroll
    for (int ni = 0; ni < 4; ++ni) es_v[ni] = esq[col0 + wn * 64 + ni * 16 + fr];

#pragma unroll
    for (int mi = 0; mi < 4; ++mi) {
#pragma unroll
        for (int q = 0; q < 4; ++q) {
            const int r = wm * 64 + mi * 16 + s4 * 4 + q;
            const float xs = xsq[row0 + r];
            float b = FLT_BIG, s = FLT_BIG; int bi = 0;
#pragma unroll
            for (int ni = 0; ni < 4; ++ni) {
                float d = (xs - 2.0f * acc[mi][ni][q]) + es_v[ni];
                int c = col0 + wn * 64 + ni * 16 + fr;
                if (d < b) { s = b; b = d; bi = c; }
                else       { s = fminf(s, d); }
            }
#pragma unroll
            for (int m = 1; m < 16; m <<= 1) {
                float b2 = __shfl_xor(b, m);
                float s2 = __shfl_xor(s, m);
                int   i2 = __shfl_xor(bi, m);
                if (b2 < b || (b2 == b && i2 < bi)) { s = fminf(b, s2); b = b2; bi = i2; }
                else                                { s = fminf(s, b2); }
            }
            if (fr == 0) { bB[r * 2 + wn] = b; sB[r * 2 + wn] = s; iB[r * 2 + wn] = bi; }
        }
    }
    __syncthreads();
    if (tid < 128) {
        float b0 = bB[tid * 2],     s0 = sB[tid * 2];     int i0 = iB[tid * 2];
        float b1 = bB[tid * 2 + 1], s1 = sB[tid * 2 + 1]; int i1 = iB[tid * 2 + 1];
        float b, s; int ix;
        if (b1 < b0) { b = b1; s = fminf(b0, s1); ix = i1; }
        else         { b = b0; s = fminf(s0, b1); ix = i0; }
        size_t o = (size_t)(row0 + tid) * 4 + bx;
        pmin[o] = b; psec[o] = s; pidx[o] = ix;
    }
}

// ---------------- merge 4 col-blocks -> idx + near-tie flags ----------------
__global__ __launch_bounds__(256)
void merge_flag(const float* __restrict__ pmin, const float* __restrict__ psec,
                const int* __restrict__ pidx, int* __restrict__ idx_int,
                float* __restrict__ idx_f, int* __restrict__ rowlist,
                int* __restrict__ nflag) {
    int row = blockIdx.x * 256 + threadIdx.x;
    size_t base = (size_t)row * 4;
    float b = pmin[base], sde = psec[base]; int ix = pidx[base];
#pragma unroll
    for (int nb = 1; nb < 4; ++nb) {
        float b2 = pmin[base + nb], s2 = psec[base + nb];
        if (b2 < b) { sde = fminf(b, s2); b = b2; ix = pidx[base + nb]; }
        else        { sde = fminf(sde, b2); }
    }
    idx_int[row] = ix;
    idx_f[row] = (float)ix;
    if (sde - b < GAP_EPS) {
        int p = atomicAdd(nflag, 1);
        rowlist[p] = row;
    }
}

// ---------------- exact recompute of near-tie rows (numpy-bit-exact) ----------
__global__ __launch_bounds__(256)
void refine_rows(const float* __restrict__ h, const float* __restrict__ enc_w,
                 const float* __restrict__ enc_b, const float* __restrict__ cb,
                 const float* __restrict__ esq, const int* __restrict__ rowlist,
                 const int* __restrict__ nflag_p, int* __restrict__ idx_int,
                 float* __restrict__ idx_f)
{
    __shared__ __align__(16) float x[C_DIM];
    __shared__ float xs_sh;
    __shared__ float rb[256];
    __shared__ int   ri[256];
    const int tid = threadIdx.x;
    const int nf = *nflag_p;
    for (int fi = blockIdx.x; fi < nf; fi += gridDim.x) {
        const int row = rowlist[fi];
        const int bt = row >> 2, seg = row & 3;
        if (tid < C_DIM) {
            const float* hp = h + (size_t)bt * D_DIM;
            const float* wp = enc_w + (size_t)(seg * C_DIM + tid) * D_DIM;
            float acc = 0.f, accC = 0.f;
            int fold = 96;   // 384/4
#pragma unroll 8
            for (int d = 0; d < D_DIM; d += 4) {
                float4 hv = *(const float4*)(hp + d);
                float4 wv = *(const float4*)(wp + d);
                accC = fmaf(hv.x, wv.x, accC);
                accC = fmaf(hv.y, wv.y, accC);
                accC = fmaf(hv.z, wv.z, accC);
                accC = fmaf(hv.w, wv.w, accC);
                if (--fold == 0) { acc = __fadd_rn(acc, accC); accC = 0.f; fold = 96; }
            }
            acc = __fadd_rn(acc, accC);   // K%384=128 remainder
            x[tid] = __fadd_rn(acc, enc_b[seg * C_DIM + tid]);
        }
        __syncthreads();
        if (tid == 0) {
            float rj[8];
#pragma unroll
            for (int j = 0; j < 8; ++j) rj[j] = __fmul_rn(x[j], x[j]);
            for (int i = 1; i < 16; ++i)
#pragma unroll
                for (int j = 0; j < 8; ++j)
                    rj[j] = __fadd_rn(rj[j], __fmul_rn(x[i * 8 + j], x[i * 8 + j]));
            float a01 = __fadd_rn(rj[0], rj[1]);
            float a23 = __fadd_rn(rj[2], rj[3]);
            float a45 = __fadd_rn(rj[4], rj[5]);
            float a67 = __fadd_rn(rj[6], rj[7]);
            xs_sh = __fadd_rn(__fadd_rn(a01, a23), __fadd_rn(a45, a67));
        }
        __syncthreads();
        const float xs = xs_sh;
        float best; int bi;
        {
            const int c0 = tid * 2;
            const float* e0 = cb + (size_t)c0 * C_DIM;
            float dot0 = 0.f, dot1 = 0.f;
#pragma unroll 4
            for (int c = 0; c < C_DIM; c += 4) {
                float4 xv  = *(const float4*)&x[c];
                float4 ev0 = *(const float4*)(e0 + c);
                float4 ev1 = *(const float4*)(e0 + C_DIM + c);
                dot0 = fmaf(xv.x, ev0.x, dot0); dot0 = fmaf(xv.y, ev0.y, dot0);
                dot0 = fmaf(xv.z, ev0.z, dot0); dot0 = fmaf(xv.w, ev0.w, dot0);
                dot1 = fmaf(xv.x, ev1.x, dot1); dot1 = fmaf(xv.y, ev1.y, dot1);
                dot1 = fmaf(xv.z, ev1.z, dot1); dot1 = fmaf(xv.w, ev1.w, dot1);
            }
            float d0 = __fadd_rn(__fsub_rn(xs, __fmul_rn(2.0f, dot0)), esq[c0]);
            float d1 = __fadd_rn(__fsub_rn(xs, __fmul_rn(2.0f, dot1)), esq[c0 + 1]);
            if (d1 < d0) { best = d1; bi = c0 + 1; } else { best = d0; bi = c0; }
        }
        rb[tid] = best; ri[tid] = bi;
        __syncthreads();
        for (int st = 128; st; st >>= 1) {
            if (tid < st) {
                float d2 = rb[tid + st]; int i2 = ri[tid + st];
                if (d2 < rb[tid] || (d2 == rb[tid] && i2 < ri[tid])) {
                    rb[tid] = d2; ri[tid] = i2;
                }
            }
            __syncthreads();
        }
        if (tid == 0) { idx_int[row] = ri[0]; idx_f[row] = (float)ri[0]; }
        __syncthreads();
    }
}

// ---------------- histogram over final indices ----------------
__global__ __launch_bounds__(256)
void histogram_kernel(const int* __restrict__ idx_int, unsigned* __restrict__ counts) {
    __shared__ unsigned hist[NCODES];
    int t = threadIdx.x;
    hist[t] = 0u; hist[t + 256] = 0u;
    __syncthreads();
    int row = blockIdx.x * 256 + t;
    atomicAdd(&hist[idx_int[row]], 1u);
    __syncthreads();
    if (hist[t]) atomicAdd(&counts[t], hist[t]);
    if (hist[t + 256]) atomicAdd(&counts[t + 256], hist[t + 256]);
}

// ---------------- fused: loss from Fh/Fl, then overwrite Fh with Qh ----------
__global__ __launch_bounds__(256)
void loss_and_q(ushort* __restrict__ Fh, const ushort* __restrict__ Fl,
                const int* __restrict__ idx, const float* __restrict__ cb,
                const ushort* __restrict__ cbh, float* __restrict__ loss_sum) {
    size_t e0 = ((size_t)blockIdx.x * 256 + threadIdx.x) * 8;
    int n = (int)(e0 >> 7);
    int c = (int)(e0 & 127);
    int k = idx[n];
    const float4* qp = (const float4*)(cb + (size_t)k * C_DIM + c);
    float4 q0 = qp[0], q1 = qp[1];
    ushort4 h0 = *(const ushort4*)&Fh[e0], h1 = *(const ushort4*)&Fh[e0 + 4];
    ushort4 l0 = *(const ushort4*)&Fl[e0], l1 = *(const ushort4*)&Fl[e0 + 4];
    float s = 0.f, d;
    d = q0.x - (bf2f(h0.x) + bf2f(l0.x)); s += d * d;
    d = q0.y - (bf2f(h0.y) + bf2f(l0.y)); s += d * d;
    d = q0.z - (bf2f(h0.z) + bf2f(l0.z)); s += d * d;
    d = q0.w - (bf2f(h0.w) + bf2f(l0.w)); s += d * d;
    d = q1.x - (bf2f(h1.x) + bf2f(l1.x)); s += d * d;
    d = q1.y - (bf2f(h1.y) + bf2f(l1.y)); s += d * d;
    d = q1.z - (bf2f(h1.z) + bf2f(l1.z)); s += d * d;
    d = q1.w - (bf2f(h1.w) + bf2f(l1.w)); s += d * d;

    // overwrite Fh with gathered bf16-hi code row (decoder A-operand)
    uint4 vh = *(const uint4*)&cbh[(size_t)k * C_DIM + c];
    *(uint4*)&Fh[e0] = vh;

    __shared__ float redf[256];
    redf[threadIdx.x] = s;
    __syncthreads();
    for (int st = 128; st; st >>= 1) {
        if (threadIdx.x < st) redf[threadIdx.x] += redf[threadIdx.x + st];
        __syncthreads();
    }
    if (threadIdx.x == 0) atomicAdd(loss_sum, redf[0]);
}

// ---------------- decoder: Qh x (Wh+Wl) MFMA GEMM, BK=64 ----------
__global__ __launch_bounds__(256)
void dec_gemm_bf16(const ushort* __restrict__ Qh, const ushort* __restrict__ Wh,
                   const ushort* __restrict__ Wl, const float* __restrict__ bias,
                   float* __restrict__ C)
{
    constexpr int Kd = 512, Nd = 2048;
    __shared__ ushort Ahs[2][4096], Bhs[2][4096], Bls[2][4096];
    const int gid = blockIdx.x;                       // 4096 blocks
    const int f   = (gid & 7) * 512 + (gid >> 3);
    const int bx  = f & 15, by = f >> 4;
    const int tid  = threadIdx.x;
    const int lane = tid & 63, wave = tid >> 6;
    const int wm = wave >> 1, wn = wave & 1;
    const int row0 = by * 128, col0 = bx * 128;

    f32x4 acc[4][4];
#pragma unroll
    for (int i = 0; i < 4; ++i)
#pragma unroll
        for (int j = 0; j < 4; ++j)
#pragma unroll
            for (int q = 0; q < 4; ++q) acc[i][j][q] = 0.f;

    const int fr = lane & 15, s4 = lane >> 4;

#define DEC_STAGE(p, kt) do {                                                         \
    _Pragma("unroll")                                                                 \
    for (int r = 0; r < 2; ++r) {                                                     \
        const int t2 = r * 256 + wave * 64 + lane;                                    \
        const int ro = t2 >> 2, sb = t2 & 3;                                          \
        const int base = (r * 256 + wave * 64) * 8;                                   \
        const size_t ga = (size_t)(row0 + ro) * Kd + (kt) * 32 + sb * 8;              \
        const size_t gb = (size_t)(col0 + ro) * Kd + (kt) * 32 + sb * 8;              \
        __builtin_amdgcn_global_load_lds(AS1(Qh + ga), AS3(&Ahs[p][base]), 16, 0, 0); \
        __builtin_amdgcn_global_load_lds(AS1(Wh + gb), AS3(&Bhs[p][base]), 16, 0, 0); \
        __builtin_amdgcn_global_load_lds(AS1(Wl + gb), AS3(&Bls[p][base]), 16, 0, 0); \
    }                                                                                 \
} while (0)

#pragma unroll 1
    for (int kt2 = 0; kt2 < Kd / 64; ++kt2) {   // 8 barrier periods
        DEC_STAGE(0, kt2 * 2);
        DEC_STAGE(1, kt2 * 2 + 1);
        __syncthreads();
        MFMA_COMPUTE2(0);
        MFMA_COMPUTE2(1);
        __syncthreads();
    }
#undef DEC_STAGE

#pragma unroll
    for (int ni = 0; ni < 4; ++ni) {
        const int c = col0 + wn * 64 + ni * 16 + fr;
        const float bv = bias[c];
#pragma unroll
        for (int mi = 0; mi < 4; ++mi) {
            const int r = row0 + wm * 64 + mi * 16 + s4 * 4;
#pragma unroll
            for (int q = 0; q < 4; ++q)
                C[(size_t)(r + q) * Nd + c] = acc[mi][ni][q] + bv;
        }
    }
}

// ---------------- scalars ----------------
__global__ __launch_bounds__(512)
void finalize_scalars(const unsigned* __restrict__ counts,
                      const float* __restrict__ loss_sum, float* __restrict__ out5) {
    __shared__ float rent[512];
    __shared__ float ruse[512];
    int t = threadIdx.x;
    float c = (float)counts[t];
    float avg = c * (1.0f / (float)NROWS);
    rent[t] = avg * logf(avg + 1e-10f);
    ruse[t] = counts[t] > 0u ? 1.f : 0.f;
    __syncthreads();
    for (int st = 256; st; st >>= 1) {
        if (t < st) { rent[t] += rent[t + st]; ruse[t] += ruse[t + st]; }
        __syncthreads();
    }
    if (t == 0) {
        float H = -rent[0];
        float perp = expf(H);
        float cl = loss_sum[0] * (1.0f / (float)NELEM);
        out5[0] = cl + 0.25f * cl;
        out5[1] = cl;
        out5[2] = cl;
        out5[3] = perp;
        out5[4] = ruse[0] * (1.0f / (float)NCODES);
    }
}

extern "C" void kernel_launch(void* const* d_in, const int* in_sizes, int n_in,
                              void* d_out, int out_size, void* d_ws, size_t ws_size,
                              hipStream_t stream) {
    const float* h     = (const float*)d_in[0];
    const float* enc_w = (const float*)d_in[1];
    const float* enc_b = (const float*)d_in[2];
    const float* cb    = (const float*)d_in[3];
    const float* dec_w = (const float*)d_in[4];
    const float* dec_b = (const float*)d_in[5];
    float* out = (float*)d_out;

    float* ws = (float*)d_ws;
    ushort*   Fh       = (ushort*)ws;                // [0, 8388608)f
    ushort*   Fl       = (ushort*)(ws + 8388608);    // [8388608, 16777216)f
    float*    xsq      = ws + 16777216;              // 131072
    float*    pmin     = ws + 16908288;              // 524288
    float*    psec     = ws + 17432576;              // 524288
    int*      pidx     = (int*)(ws + 17956864);      // 524288
    int*      idx_int  = (int*)(ws + 18481152);      // 131072
    int*      rowlist  = (int*)(ws + 18612224);      // 131072
    float*    esq      = ws + 18743296;              // 512
    unsigned* counts   = (unsigned*)(ws + 18743808); // 512
    float*    loss_sum = ws + 18744320;              // 1
    int*      nflag    = (int*)(ws + 18744321);      // 1

    // overlays (hosts dead when used). cb split planes each = 32768 float-slots.
    ushort* EWh  = (ushort*)(ws + 16908288);         // over pmin  (pre-dist)
    ushort* EWl  = (ushort*)(ws + 17432576);         // over psec  (pre-dist)
    ushort* cbhd = (ushort*)(ws + 18612224);         // over rowlist[0..32767]   (pre-merge)
    ushort* cbld = (ushort*)(ws + 18644992);         // over rowlist[32768..65535]
    ushort* cbh  = (ushort*)(ws + 16777216);         // over xsq[0..32767]       (post-dist)
    ushort* Wh   = (ushort*)(ws + 16908288);         // over pmin (post-merge)
    ushort* Wl   = (ushort*)(ws + 17432576);         // over psec (post-merge)

    float* msg_out = out;                     // 67108864
    float* idx_out = out + 67108864;          // 131072
    float* sc_out  = out + 67108864 + 131072; // 5

    zero_kernel<<<1, 512, 0, stream>>>(counts, loss_sum, nflag);
    sq_pairwise<<<NCODES / 32, 256, 0, stream>>>(cb, esq, NCODES);

    split_hi_lo<<<KC_DIM * D_DIM / 4 / 256, 256, 0, stream>>>(enc_w, EWh, EWl, KC_DIM * D_DIM / 4);
    split_hi_lo<<<NCODES * C_DIM / 4 / 256, 256, 0, stream>>>(cb, cbhd, cbld, NCODES * C_DIM / 4);

    // encoder on matrix cores (BK=64) -> split-bf16 flat planes + fused xsq
    enc_mfma<<<1024, 256, 0, stream>>>(h, EWh, EWl, enc_b, Fh, Fl, xsq);

    // distances on matrix cores (BK=64) + best/second/idx
    dist_mfma<<<4096, 256, 0, stream>>>(Fh, Fl, cbhd, cbld, xsq, esq, pmin, psec, pidx);

    merge_flag<<<NROWS / 256, 256, 0, stream>>>(pmin, psec, pidx, idx_int, idx_out,
                                                rowlist, nflag);

    refine_rows<<<2048, 256, 0, stream>>>(h, enc_w, enc_b, cb, esq, rowlist, nflag,
                                          idx_int, idx_out);

    histogram_kernel<<<NROWS / 256, 256, 0, stream>>>(idx_int, counts);

    // splits for decoder (xsq / pmin / psec dead now)
    split_hi<<<NCODES * C_DIM / 4 / 256, 256, 0, stream>>>(cb, cbh, NCODES * C_DIM / 4);
    split_hi_lo<<<D_DIM * KC_DIM / 4 / 256, 256, 0, stream>>>(dec_w, Wh, Wl, D_DIM * KC_DIM / 4);

    // fused: loss from Fh/Fl, then overwrite Fh in place with Qh
    loss_and_q<<<NELEM / (256 * 8), 256, 0, stream>>>(Fh, Fl, idx_int, cb, cbh, loss_sum);

    // decoder (BK=64, 2-product): message = Qh @ (Wh+Wl)^T + b
    dec_gemm_bf16<<<4096, 256, 0, stream>>>(Fh, Wh, Wl, dec_b, msg_out);

    finalize_scalars<<<1, 512, 0, stream>>>(counts, loss_sum, sc_out);
}

// Round 19
// 673.459 us; speedup vs baseline: 1.4415x; 1.1516x over previous
//
#include <hip/hip_runtime.h>
#include <hip/hip_bf16.h>

// B=16, T=2048, D=2048, K(msg)=4, C=128, KC=512, CODEBOOK=512
#define M_BT      32768
#define KC_DIM    512
#define D_DIM     2048
#define C_DIM     128
#define NROWS     131072
#define NCODES    512
#define NELEM     16777216   // NROWS*C_DIM
#define GAP_EPS   6.0e-4f
#define FLT_BIG   3.4028235e38f

typedef __bf16 bf16x8 __attribute__((ext_vector_type(8)));
typedef float  f32x4  __attribute__((ext_vector_type(4)));

#define AS3(p) ((__attribute__((address_space(3))) void*)(p))
#define AS1(p) ((const __attribute__((address_space(1))) void*)(p))

static __device__ __forceinline__ ushort f2bf(float x) {
    __bf16 b = (__bf16)x;
    return __builtin_bit_cast(ushort, b);
}
static __device__ __forceinline__ float bf2f(ushort u) {
    return __uint_as_float(((unsigned)u) << 16);
}
static __device__ __forceinline__ void split1(float x, ushort& hi, ushort& lo) {
    __bf16 b = (__bf16)x;
    hi = __builtin_bit_cast(ushort, b);
    lo = __builtin_bit_cast(ushort, (__bf16)(x - (float)b));
}

// 3-product MFMA from subtile plane p (enc/dist)
#define MFMA_COMPUTE(p) do {                                                          \
    bf16x8 ah[4], al[4], bh[4], bl[4];                                                \
    _Pragma("unroll")                                                                 \
    for (int mi = 0; mi < 4; ++mi) {                                                  \
        const int off = (wm * 64 + mi * 16 + fr) * 32 + s4 * 8;                       \
        ah[mi] = *(const bf16x8*)&Ahs[p][off];                                        \
        al[mi] = *(const bf16x8*)&Als[p][off];                                        \
    }                                                                                 \
    _Pragma("unroll")                                                                 \
    for (int ni = 0; ni < 4; ++ni) {                                                  \
        const int off = (wn * 64 + ni * 16 + fr) * 32 + s4 * 8;                       \
        bh[ni] = *(const bf16x8*)&Bhs[p][off];                                        \
        bl[ni] = *(const bf16x8*)&Bls[p][off];                                        \
    }                                                                                 \
    _Pragma("unroll")                                                                 \
    for (int mi = 0; mi < 4; ++mi)                                                    \
        _Pragma("unroll")                                                             \
        for (int ni = 0; ni < 4; ++ni) {                                              \
            acc[mi][ni] = __builtin_amdgcn_mfma_f32_16x16x32_bf16(ah[mi], bh[ni], acc[mi][ni], 0, 0, 0); \
            acc[mi][ni] = __builtin_amdgcn_mfma_f32_16x16x32_bf16(ah[mi], bl[ni], acc[mi][ni], 0, 0, 0); \
            acc[mi][ni] = __builtin_amdgcn_mfma_f32_16x16x32_bf16(al[mi], bh[ni], acc[mi][ni], 0, 0, 0); \
        }                                                                             \
} while (0)

// 2-product MFMA (decoder: Qh x (Wh + Wl))
#define MFMA_COMPUTE2(p) do {                                                         \
    bf16x8 ah[4], bh[4], bl[4];                                                       \
    _Pragma("unroll")                                                                 \
    for (int mi = 0; mi < 4; ++mi) {                                                  \
        const int off = (wm * 64 + mi * 16 + fr) * 32 + s4 * 8;                       \
        ah[mi] = *(const bf16x8*)&Ahs[p][off];                                        \
    }                                                                                 \
    _Pragma("unroll")                                                                 \
    for (int ni = 0; ni < 4; ++ni) {                                                  \
        const int off = (wn * 64 + ni * 16 + fr) * 32 + s4 * 8;                       \
        bh[ni] = *(const bf16x8*)&Bhs[p][off];                                        \
        bl[ni] = *(const bf16x8*)&Bls[p][off];                                        \
    }                                                                                 \
    _Pragma("unroll")                                                                 \
    for (int mi = 0; mi < 4; ++mi)                                                    \
        _Pragma("unroll")                                                             \
        for (int ni = 0; ni < 4; ++ni) {                                              \
            acc[mi][ni] = __builtin_amdgcn_mfma_f32_16x16x32_bf16(ah[mi], bh[ni], acc[mi][ni], 0, 0, 0); \
            acc[mi][ni] = __builtin_amdgcn_mfma_f32_16x16x32_bf16(ah[mi], bl[ni], acc[mi][ni], 0, 0, 0); \
        }                                                                             \
} while (0)

// ---------------- zero counters ----------------
__global__ __launch_bounds__(512)
void zero_kernel(unsigned* __restrict__ counts, float* __restrict__ loss_sum,
                 int* __restrict__ nflag) {
    counts[threadIdx.x] = 0u;
    if (threadIdx.x == 0) { loss_sum[0] = 0.f; nflag[0] = 0; }
}

// ---------------- numpy-pairwise sum of squares (fp32 input, for e_sq) --------
__global__ __launch_bounds__(256)
void sq_pairwise(const float* __restrict__ src, float* __restrict__ dst, int nrows) {
    int t = threadIdx.x;
    int row = blockIdx.x * 32 + (t >> 3);
    int j = t & 7;
    if (row >= nrows) return;
    const float* p = src + (size_t)row * C_DIM + j;
    float v = p[0];
    float r = __fmul_rn(v, v);
#pragma unroll
    for (int i = 1; i < 16; ++i) {
        float u = p[i * 8];
        r = __fadd_rn(r, __fmul_rn(u, u));
    }
    r = __fadd_rn(r, __shfl_xor(r, 1));
    r = __fadd_rn(r, __shfl_xor(r, 2));
    r = __fadd_rn(r, __shfl_xor(r, 4));
    if (j == 0) dst[row] = r;
}

// ---------------- split fp32 matrix into bf16 hi+lo ----------------
__global__ __launch_bounds__(256)
void split_hi_lo(const float* __restrict__ src, ushort* __restrict__ hi,
                 ushort* __restrict__ lo, int n4) {
    int e = blockIdx.x * 256 + threadIdx.x;
    if (e >= n4) return;
    float4 v = *(const float4*)&src[(size_t)e * 4];
    ushort4 H, L;
    split1(v.x, H.x, L.x); split1(v.y, H.y, L.y);
    split1(v.z, H.z, L.z); split1(v.w, H.w, L.w);
    *(ushort4*)&hi[(size_t)e * 4] = H;
    *(ushort4*)&lo[(size_t)e * 4] = L;
}

// ---------------- split fp32 matrix into bf16 hi only ----------------
__global__ __launch_bounds__(256)
void split_hi(const float* __restrict__ src, ushort* __restrict__ hi, int n4) {
    int e = blockIdx.x * 256 + threadIdx.x;
    if (e >= n4) return;
    float4 v = *(const float4*)&src[(size_t)e * 4];
    ushort4 H;
    H.x = f2bf(v.x); H.y = f2bf(v.y); H.z = f2bf(v.z); H.w = f2bf(v.w);
    *(ushort4*)&hi[(size_t)e * 4] = H;
}

// ---------------- encoder: split-bf16 MFMA GEMM, BK=64, fused xsq ----------
__global__ __launch_bounds__(256)
void enc_mfma(const float* __restrict__ h, const ushort* __restrict__ EWh,
              const ushort* __restrict__ EWl, const float* __restrict__ bias,
              ushort* __restrict__ Fh, ushort* __restrict__ Fl,
              float* __restrict__ xsq)
{
    constexpr int K = D_DIM, N = KC_DIM;
    __shared__ ushort Ahs[2][4096], Als[2][4096], Bhs[2][4096], Bls[2][4096];
    const int gid = blockIdx.x;                 // 1024 blocks
    const int f   = (gid & 7) * 128 + (gid >> 3);
    const int bx  = f & 3, by = f >> 2;         // 4 col-blocks, 256 row-blocks
    const int row0 = by * 128, col0 = bx * 128;
    const int tid  = threadIdx.x;
    const int lane = tid & 63, wave = tid >> 6;
    const int wm = wave >> 1, wn = wave & 1;

    f32x4 acc[4][4];
#pragma unroll
    for (int i = 0; i < 4; ++i)
#pragma unroll
        for (int j = 0; j < 4; ++j)
#pragma unroll
            for (int q = 0; q < 4; ++q) acc[i][j][q] = 0.f;

    const int fr = lane & 15, s4 = lane >> 4;
    const int arow = tid >> 3, ak8 = tid & 7;

#define ENC_STAGE(p, kt) do {                                                         \
    _Pragma("unroll")                                                                 \
    for (int r = 0; r < 2; ++r) {                                                     \
        const int t2 = r * 256 + wave * 64 + lane;                                    \
        const int ro = t2 >> 2, sb = t2 & 3;                                          \
        const int base = (r * 256 + wave * 64) * 8;                                   \
        const size_t gb = (size_t)(col0 + ro) * K + (kt) * 32 + sb * 8;               \
        __builtin_amdgcn_global_load_lds(AS1(EWh + gb), AS3(&Bhs[p][base]), 16, 0, 0);\
        __builtin_amdgcn_global_load_lds(AS1(EWl + gb), AS3(&Bls[p][base]), 16, 0, 0);\
    }                                                                                 \
    _Pragma("unroll")                                                                 \
    for (int q = 0; q < 4; ++q) {                                                     \
        const int row = q * 32 + arow;                                                \
        float4 v = *(const float4*)&h[(size_t)(row0 + row) * K + (kt) * 32 + ak8 * 4];\
        ushort4 H, L;                                                                 \
        split1(v.x, H.x, L.x); split1(v.y, H.y, L.y);                                 \
        split1(v.z, H.z, L.z); split1(v.w, H.w, L.w);                                 \
        *(ushort4*)&Ahs[p][row * 32 + ak8 * 4] = H;                                   \
        *(ushort4*)&Als[p][row * 32 + ak8 * 4] = L;                                   \
    }                                                                                 \
} while (0)

#pragma unroll 1
    for (int kt2 = 0; kt2 < K / 64; ++kt2) {    // 32 barrier periods
        ENC_STAGE(0, kt2 * 2);
        ENC_STAGE(1, kt2 * 2 + 1);
        __syncthreads();
        MFMA_COMPUTE(0);
        MFMA_COMPUTE(1);
        __syncthreads();
    }
#undef ENC_STAGE

    // epilogue: store split-bf16 flat + accumulate row sum-of-squares
    float ss[4][4];
#pragma unroll
    for (int mi = 0; mi < 4; ++mi)
#pragma unroll
        for (int q = 0; q < 4; ++q) ss[mi][q] = 0.f;

#pragma unroll
    for (int ni = 0; ni < 4; ++ni) {
        const int c = col0 + wn * 64 + ni * 16 + fr;
        const float bv = bias[c];
#pragma unroll
        for (int mi = 0; mi < 4; ++mi) {
            const int r = row0 + wm * 64 + mi * 16 + s4 * 4;
#pragma unroll
            for (int q = 0; q < 4; ++q) {
                float val = acc[mi][ni][q] + bv;
                ushort hi, lo;
                split1(val, hi, lo);
                size_t e = (size_t)(r + q) * N + c;
                Fh[e] = hi;
                Fl[e] = lo;
                ss[mi][q] += val * val;
            }
        }
    }
    // reduce ssq: 16 lanes (fr) per 16-group, then wn halves via LDS
    float* xpart = (float*)&Ahs[0][0];   // [128][2]
#pragma unroll
    for (int mi = 0; mi < 4; ++mi)
#pragma unroll
        for (int q = 0; q < 4; ++q) {
            float s = ss[mi][q];
            s += __shfl_xor(s, 1); s += __shfl_xor(s, 2);
            s += __shfl_xor(s, 4); s += __shfl_xor(s, 8);
            ss[mi][q] = s;
        }
    if (fr == 0) {
#pragma unroll
        for (int mi = 0; mi < 4; ++mi)
#pragma unroll
            for (int q = 0; q < 4; ++q)
                xpart[(wm * 64 + mi * 16 + s4 * 4 + q) * 2 + wn] = ss[mi][q];
    }
    __syncthreads();
    if (tid < 128)
        xsq[(size_t)(row0 + tid) * 4 + bx] = xpart[tid * 2] + xpart[tid * 2 + 1];
}

// ---------------- dist on matrix cores: all-bf16, BK=64 ----------
__global__ __launch_bounds__(256)
void dist_mfma(const ushort* __restrict__ Fh, const ushort* __restrict__ Fl,
               const ushort* __restrict__ cbh, const ushort* __restrict__ cbl,
               const float* __restrict__ xsq, const float* __restrict__ esq,
               float* __restrict__ pmin, float* __restrict__ psec,
               int* __restrict__ pidx)
{
    constexpr int K = C_DIM;                    // 128
    __shared__ ushort Ahs[2][4096], Als[2][4096], Bhs[2][4096], Bls[2][4096];
    const int gid = blockIdx.x;                 // 4096 blocks
    const int f   = (gid & 7) * 512 + (gid >> 3);
    const int bx  = f & 3, by = f >> 2;         // 4 col-blocks, 1024 row-blocks
    const int row0 = by * 128, col0 = bx * 128;
    const int tid  = threadIdx.x;
    const int lane = tid & 63, wave = tid >> 6;
    const int wm = wave >> 1, wn = wave & 1;

    f32x4 acc[4][4];
#pragma unroll
    for (int i = 0; i < 4; ++i)
#pragma unroll
        for (int j = 0; j < 4; ++j)
#pragma unroll
            for (int q = 0; q < 4; ++q) acc[i][j][q] = 0.f;

    const int fr = lane & 15, s4 = lane >> 4;

#define DIST_STAGE(p, kt) do {                                                        \
    _Pragma("unroll")                                                                 \
    for (int r = 0; r < 2; ++r) {                                                     \
        const int t2 = r * 256 + wave * 64 + lane;                                    \
        const int ro = t2 >> 2, sb = t2 & 3;                                          \
        const int base = (r * 256 + wave * 64) * 8;                                   \
        const size_t ga = (size_t)(row0 + ro) * K + (kt) * 32 + sb * 8;               \
        const size_t gb = (size_t)(col0 + ro) * K + (kt) * 32 + sb * 8;               \
        __builtin_amdgcn_global_load_lds(AS1(Fh + ga),  AS3(&Ahs[p][base]), 16, 0, 0);\
        __builtin_amdgcn_global_load_lds(AS1(Fl + ga),  AS3(&Als[p][base]), 16, 0, 0);\
        __builtin_amdgcn_global_load_lds(AS1(cbh + gb), AS3(&Bhs[p][base]), 16, 0, 0);\
        __builtin_amdgcn_global_load_lds(AS1(cbl + gb), AS3(&Bls[p][base]), 16, 0, 0);\
    }                                                                                 \
} while (0)

#pragma unroll 1
    for (int kt2 = 0; kt2 < K / 64; ++kt2) {    // 2 barrier periods
        DIST_STAGE(0, kt2 * 2);
        DIST_STAGE(1, kt2 * 2 + 1);
        __syncthreads();
        MFMA_COMPUTE(0);
        MFMA_COMPUTE(1);
        __syncthreads();
    }
#undef DIST_STAGE

    // epilogue: dist + per-row (best, second, idx). LDS scratch aliases Ahs/Als
    float* bB = (float*)&Ahs[0][0];          // [128][2]
    float* sB = (float*)&Ahs[0][0] + 256;    // [128][2]
    int*   iB = (int*)&Als[0][0];            // [128][2]

    float es_v[4];
#pragma unroll
    for (int ni = 0; ni < 4; ++ni) es_v[ni] = esq[col0 + wn * 64 + ni * 16 + fr];

#pragma unroll
    for (int mi = 0; mi < 4; ++mi) {
#pragma unroll
        for (int q = 0; q < 4; ++q) {
            const int r = wm * 64 + mi * 16 + s4 * 4 + q;
            const float xs = xsq[row0 + r];
            float b = FLT_BIG, s = FLT_BIG; int bi = 0;
#pragma unroll
            for (int ni = 0; ni < 4; ++ni) {
                float d = (xs - 2.0f * acc[mi][ni][q]) + es_v[ni];
                int c = col0 + wn * 64 + ni * 16 + fr;
                if (d < b) { s = b; b = d; bi = c; }
                else       { s = fminf(s, d); }
            }
#pragma unroll
            for (int m = 1; m < 16; m <<= 1) {
                float b2 = __shfl_xor(b, m);
                float s2 = __shfl_xor(s, m);
                int   i2 = __shfl_xor(bi, m);
                if (b2 < b || (b2 == b && i2 < bi)) { s = fminf(b, s2); b = b2; bi = i2; }
                else                                { s = fminf(s, b2); }
            }
            if (fr == 0) { bB[r * 2 + wn] = b; sB[r * 2 + wn] = s; iB[r * 2 + wn] = bi; }
        }
    }
    __syncthreads();
    if (tid < 128) {
        float b0 = bB[tid * 2],     s0 = sB[tid * 2];     int i0 = iB[tid * 2];
        float b1 = bB[tid * 2 + 1], s1 = sB[tid * 2 + 1]; int i1 = iB[tid * 2 + 1];
        float b, s; int ix;
        if (b1 < b0) { b = b1; s = fminf(b0, s1); ix = i1; }
        else         { b = b0; s = fminf(s0, b1); ix = i0; }
        size_t o = (size_t)(row0 + tid) * 4 + bx;
        pmin[o] = b; psec[o] = s; pidx[o] = ix;
    }
}

// ---------------- merge 4 col-blocks -> idx + flags + loss accumulation -------
__global__ __launch_bounds__(256)
void merge_flag(const float* __restrict__ pmin, const float* __restrict__ psec,
                const int* __restrict__ pidx, int* __restrict__ idx_int,
                float* __restrict__ idx_f, int* __restrict__ rowlist,
                int* __restrict__ nflag, float* __restrict__ loss_sum) {
    int row = blockIdx.x * 256 + threadIdx.x;
    size_t base = (size_t)row * 4;
    float b = pmin[base], sde = psec[base]; int ix = pidx[base];
#pragma unroll
    for (int nb = 1; nb < 4; ++nb) {
        float b2 = pmin[base + nb], s2 = psec[base + nb];
        if (b2 < b) { sde = fminf(b, s2); b = b2; ix = pidx[base + nb]; }
        else        { sde = fminf(sde, b2); }
    }
    idx_int[row] = ix;
    idx_f[row] = (float)ix;
    if (sde - b < GAP_EPS) {
        int p = atomicAdd(nflag, 1);
        rowlist[p] = row;
    }
    // loss: sum of min distances == sum_rows ||f - cb[idx]||^2
    __shared__ float redf[256];
    redf[threadIdx.x] = b;
    __syncthreads();
    for (int st = 128; st; st >>= 1) {
        if (threadIdx.x < st) redf[threadIdx.x] += redf[threadIdx.x + st];
        __syncthreads();
    }
    if (threadIdx.x == 0) atomicAdd(loss_sum, redf[0]);
}

// ---------------- exact recompute of near-tie rows (numpy-bit-exact) ----------
__global__ __launch_bounds__(256)
void refine_rows(const float* __restrict__ h, const float* __restrict__ enc_w,
                 const float* __restrict__ enc_b, const float* __restrict__ cb,
                 const float* __restrict__ esq, const int* __restrict__ rowlist,
                 const int* __restrict__ nflag_p, int* __restrict__ idx_int,
                 float* __restrict__ idx_f)
{
    __shared__ __align__(16) float x[C_DIM];
    __shared__ float xs_sh;
    __shared__ float rb[256];
    __shared__ int   ri[256];
    const int tid = threadIdx.x;
    const int nf = *nflag_p;
    for (int fi = blockIdx.x; fi < nf; fi += gridDim.x) {
        const int row = rowlist[fi];
        const int bt = row >> 2, seg = row & 3;
        if (tid < C_DIM) {
            const float* hp = h + (size_t)bt * D_DIM;
            const float* wp = enc_w + (size_t)(seg * C_DIM + tid) * D_DIM;
            float acc = 0.f, accC = 0.f;
            int fold = 96;   // 384/4
#pragma unroll 8
            for (int d = 0; d < D_DIM; d += 4) {
                float4 hv = *(const float4*)(hp + d);
                float4 wv = *(const float4*)(wp + d);
                accC = fmaf(hv.x, wv.x, accC);
                accC = fmaf(hv.y, wv.y, accC);
                accC = fmaf(hv.z, wv.z, accC);
                accC = fmaf(hv.w, wv.w, accC);
                if (--fold == 0) { acc = __fadd_rn(acc, accC); accC = 0.f; fold = 96; }
            }
            acc = __fadd_rn(acc, accC);   // K%384=128 remainder
            x[tid] = __fadd_rn(acc, enc_b[seg * C_DIM + tid]);
        }
        __syncthreads();
        if (tid == 0) {
            float rj[8];
#pragma unroll
            for (int j = 0; j < 8; ++j) rj[j] = __fmul_rn(x[j], x[j]);
            for (int i = 1; i < 16; ++i)
#pragma unroll
                for (int j = 0; j < 8; ++j)
                    rj[j] = __fadd_rn(rj[j], __fmul_rn(x[i * 8 + j], x[i * 8 + j]));
            float a01 = __fadd_rn(rj[0], rj[1]);
            float a23 = __fadd_rn(rj[2], rj[3]);
            float a45 = __fadd_rn(rj[4], rj[5]);
            float a67 = __fadd_rn(rj[6], rj[7]);
            xs_sh = __fadd_rn(__fadd_rn(a01, a23), __fadd_rn(a45, a67));
        }
        __syncthreads();
        const float xs = xs_sh;
        float best; int bi;
        {
            const int c0 = tid * 2;
            const float* e0 = cb + (size_t)c0 * C_DIM;
            float dot0 = 0.f, dot1 = 0.f;
#pragma unroll 4
            for (int c = 0; c < C_DIM; c += 4) {
                float4 xv  = *(const float4*)&x[c];
                float4 ev0 = *(const float4*)(e0 + c);
                float4 ev1 = *(const float4*)(e0 + C_DIM + c);
                dot0 = fmaf(xv.x, ev0.x, dot0); dot0 = fmaf(xv.y, ev0.y, dot0);
                dot0 = fmaf(xv.z, ev0.z, dot0); dot0 = fmaf(xv.w, ev0.w, dot0);
                dot1 = fmaf(xv.x, ev1.x, dot1); dot1 = fmaf(xv.y, ev1.y, dot1);
                dot1 = fmaf(xv.z, ev1.z, dot1); dot1 = fmaf(xv.w, ev1.w, dot1);
            }
            float d0 = __fadd_rn(__fsub_rn(xs, __fmul_rn(2.0f, dot0)), esq[c0]);
            float d1 = __fadd_rn(__fsub_rn(xs, __fmul_rn(2.0f, dot1)), esq[c0 + 1]);
            if (d1 < d0) { best = d1; bi = c0 + 1; } else { best = d0; bi = c0; }
        }
        rb[tid] = best; ri[tid] = bi;
        __syncthreads();
        for (int st = 128; st; st >>= 1) {
            if (tid < st) {
                float d2 = rb[tid + st]; int i2 = ri[tid + st];
                if (d2 < rb[tid] || (d2 == rb[tid] && i2 < ri[tid])) {
                    rb[tid] = d2; ri[tid] = i2;
                }
            }
            __syncthreads();
        }
        if (tid == 0) { idx_int[row] = ri[0]; idx_f[row] = (float)ri[0]; }
        __syncthreads();
    }
}

// ---------------- histogram over final indices ----------------
__global__ __launch_bounds__(256)
void histogram_kernel(const int* __restrict__ idx_int, unsigned* __restrict__ counts) {
    __shared__ unsigned hist[NCODES];
    int t = threadIdx.x;
    hist[t] = 0u; hist[t + 256] = 0u;
    __syncthreads();
    int row = blockIdx.x * 256 + t;
    atomicAdd(&hist[idx_int[row]], 1u);
    __syncthreads();
    if (hist[t]) atomicAdd(&counts[t], hist[t]);
    if (hist[t + 256]) atomicAdd(&counts[t + 256], hist[t + 256]);
}

// ---------------- decoder: indirect-gather A (cbh via idx), BK=64 ----------
__global__ __launch_bounds__(256)
void dec_gemm_bf16(const ushort* __restrict__ cbh, const int* __restrict__ idx,
                   const ushort* __restrict__ Wh, const ushort* __restrict__ Wl,
                   const float* __restrict__ bias, float* __restrict__ C)
{
    constexpr int Kd = 512, Nd = 2048;
    __shared__ ushort Ahs[2][4096], Bhs[2][4096], Bls[2][4096];
    __shared__ int idxL[512];
    const int gid = blockIdx.x;                       // 4096 blocks
    const int f   = (gid & 7) * 512 + (gid >> 3);
    const int bx  = f & 15, by = f >> 4;
    const int tid  = threadIdx.x;
    const int lane = tid & 63, wave = tid >> 6;
    const int wm = wave >> 1, wn = wave & 1;
    const int row0 = by * 128, col0 = bx * 128;

    // preload this block's 512 code indices (rows row0..row0+127 x 4 segs)
    idxL[tid]       = idx[(size_t)row0 * 4 + tid];
    idxL[tid + 256] = idx[(size_t)row0 * 4 + 256 + tid];

    f32x4 acc[4][4];
#pragma unroll
    for (int i = 0; i < 4; ++i)
#pragma unroll
        for (int j = 0; j < 4; ++j)
#pragma unroll
            for (int q = 0; q < 4; ++q) acc[i][j][q] = 0.f;

    const int fr = lane & 15, s4 = lane >> 4;
    __syncthreads();   // idxL ready

#define DEC_STAGE(p, kt) do {                                                         \
    _Pragma("unroll")                                                                 \
    for (int r = 0; r < 2; ++r) {                                                     \
        const int t2 = r * 256 + wave * 64 + lane;                                    \
        const int ro = t2 >> 2, sb = t2 & 3;                                          \
        const int base = (r * 256 + wave * 64) * 8;                                   \
        const int ci = idxL[ro * 4 + ((kt) >> 2)];                                    \
        const size_t ga = (size_t)ci * C_DIM + ((kt) & 3) * 32 + sb * 8;              \
        const size_t gb = (size_t)(col0 + ro) * Kd + (kt) * 32 + sb * 8;              \
        __builtin_amdgcn_global_load_lds(AS1(cbh + ga), AS3(&Ahs[p][base]), 16, 0, 0);\
        __builtin_amdgcn_global_load_lds(AS1(Wh + gb),  AS3(&Bhs[p][base]), 16, 0, 0);\
        __builtin_amdgcn_global_load_lds(AS1(Wl + gb),  AS3(&Bls[p][base]), 16, 0, 0);\
    }                                                                                 \
} while (0)

#pragma unroll 1
    for (int kt2 = 0; kt2 < Kd / 64; ++kt2) {   // 8 barrier periods
        DEC_STAGE(0, kt2 * 2);
        DEC_STAGE(1, kt2 * 2 + 1);
        __syncthreads();
        MFMA_COMPUTE2(0);
        MFMA_COMPUTE2(1);
        __syncthreads();
    }
#undef DEC_STAGE

#pragma unroll
    for (int ni = 0; ni < 4; ++ni) {
        const int c = col0 + wn * 64 + ni * 16 + fr;
        const float bv = bias[c];
#pragma unroll
        for (int mi = 0; mi < 4; ++mi) {
            const int r = row0 + wm * 64 + mi * 16 + s4 * 4;
#pragma unroll
            for (int q = 0; q < 4; ++q)
                C[(size_t)(r + q) * Nd + c] = acc[mi][ni][q] + bv;
        }
    }
}

// ---------------- scalars ----------------
__global__ __launch_bounds__(512)
void finalize_scalars(const unsigned* __restrict__ counts,
                      const float* __restrict__ loss_sum, float* __restrict__ out5) {
    __shared__ float rent[512];
    __shared__ float ruse[512];
    int t = threadIdx.x;
    float c = (float)counts[t];
    float avg = c * (1.0f / (float)NROWS);
    rent[t] = avg * logf(avg + 1e-10f);
    ruse[t] = counts[t] > 0u ? 1.f : 0.f;
    __syncthreads();
    for (int st = 256; st; st >>= 1) {
        if (t < st) { rent[t] += rent[t + st]; ruse[t] += ruse[t + st]; }
        __syncthreads();
    }
    if (t == 0) {
        float H = -rent[0];
        float perp = expf(H);
        float cl = loss_sum[0] * (1.0f / (float)NELEM);
        out5[0] = cl + 0.25f * cl;
        out5[1] = cl;
        out5[2] = cl;
        out5[3] = perp;
        out5[4] = ruse[0] * (1.0f / (float)NCODES);
    }
}

extern "C" void kernel_launch(void* const* d_in, const int* in_sizes, int n_in,
                              void* d_out, int out_size, void* d_ws, size_t ws_size,
                              hipStream_t stream) {
    const float* h     = (const float*)d_in[0];
    const float* enc_w = (const float*)d_in[1];
    const float* enc_b = (const float*)d_in[2];
    const float* cb    = (const float*)d_in[3];
    const float* dec_w = (const float*)d_in[4];
    const float* dec_b = (const float*)d_in[5];
    float* out = (float*)d_out;

    float* ws = (float*)d_ws;
    ushort*   Fh       = (ushort*)ws;                // [0, 8388608)f
    ushort*   Fl       = (ushort*)(ws + 8388608);    // [8388608, 16777216)f
    float*    xsq      = ws + 16777216;              // 131072
    float*    pmin     = ws + 16908288;              // 524288
    float*    psec     = ws + 17432576;              // 524288
    int*      pidx     = (int*)(ws + 17956864);      // 524288
    int*      idx_int  = (int*)(ws + 18481152);      // 131072
    int*      rowlist  = (int*)(ws + 18612224);      // 131072
    float*    esq      = ws + 18743296;              // 512
    unsigned* counts   = (unsigned*)(ws + 18743808); // 512
    float*    loss_sum = ws + 18744320;              // 1
    int*      nflag    = (int*)(ws + 18744321);      // 1

    // overlays (hosts dead when used). cb split planes each = 32768 float-slots.
    ushort* EWh  = (ushort*)(ws + 16908288);         // over pmin  (pre-dist)
    ushort* EWl  = (ushort*)(ws + 17432576);         // over psec  (pre-dist)
    ushort* cbhd = (ushort*)(ws + 18612224);         // over rowlist[0..32767]   (pre-merge)
    ushort* cbld = (ushort*)(ws + 18644992);         // over rowlist[32768..65535]
    ushort* cbh  = (ushort*)(ws + 16777216);         // over xsq[0..32767]       (post-dist)
    ushort* Wh   = (ushort*)(ws + 16908288);         // over pmin (post-merge)
    ushort* Wl   = (ushort*)(ws + 17432576);         // over psec (post-merge)

    float* msg_out = out;                     // 67108864
    float* idx_out = out + 67108864;          // 131072
    float* sc_out  = out + 67108864 + 131072; // 5

    zero_kernel<<<1, 512, 0, stream>>>(counts, loss_sum, nflag);
    sq_pairwise<<<NCODES / 32, 256, 0, stream>>>(cb, esq, NCODES);

    split_hi_lo<<<KC_DIM * D_DIM / 4 / 256, 256, 0, stream>>>(enc_w, EWh, EWl, KC_DIM * D_DIM / 4);
    split_hi_lo<<<NCODES * C_DIM / 4 / 256, 256, 0, stream>>>(cb, cbhd, cbld, NCODES * C_DIM / 4);

    // encoder on matrix cores (BK=64) -> split-bf16 flat planes + fused xsq
    enc_mfma<<<1024, 256, 0, stream>>>(h, EWh, EWl, enc_b, Fh, Fl, xsq);

    // distances on matrix cores (BK=64) + best/second/idx
    dist_mfma<<<4096, 256, 0, stream>>>(Fh, Fl, cbhd, cbld, xsq, esq, pmin, psec, pidx);

    // merge col-blocks: final idx + near-tie flags + loss = sum of min dists
    merge_flag<<<NROWS / 256, 256, 0, stream>>>(pmin, psec, pidx, idx_int, idx_out,
                                                rowlist, nflag, loss_sum);

    refine_rows<<<2048, 256, 0, stream>>>(h, enc_w, enc_b, cb, esq, rowlist, nflag,
                                          idx_int, idx_out);

    histogram_kernel<<<NROWS / 256, 256, 0, stream>>>(idx_int, counts);

    // splits for decoder (xsq / pmin / psec dead now)
    split_hi<<<NCODES * C_DIM / 4 / 256, 256, 0, stream>>>(cb, cbh, NCODES * C_DIM / 4);
    split_hi_lo<<<D_DIM * KC_DIM / 4 / 256, 256, 0, stream>>>(dec_w, Wh, Wl, D_DIM * KC_DIM / 4);

    // decoder (BK=64, 2-product, indirect A-gather from L2-resident cbh)
    dec_gemm_bf16<<<4096, 256, 0, stream>>>(cbh, idx_int, Wh, Wl, dec_b, msg_out);

    finalize_scalars<<<1, 512, 0, stream>>>(counts, loss_sum, sc_out);
}

// Round 20
// 610.157 us; speedup vs baseline: 1.5910x; 1.1037x over previous
//
#include <hip/hip_runtime.h>
#include <hip/hip_bf16.h>

// B=16, T=2048, D=2048, K(msg)=4, C=128, KC=512, CODEBOOK=512
#define M_BT      32768
#define KC_DIM    512
#define D_DIM     2048
#define C_DIM     128
#define NROWS     131072
#define NCODES    512
#define NELEM     16777216   // NROWS*C_DIM
#define GAP_EPS   6.0e-4f
#define FLT_BIG   3.4028235e38f

typedef __bf16 bf16x8 __attribute__((ext_vector_type(8)));
typedef float  f32x4  __attribute__((ext_vector_type(4)));

#define AS3(p) ((__attribute__((address_space(3))) void*)(p))
#define AS1(p) ((const __attribute__((address_space(1))) void*)(p))

static __device__ __forceinline__ ushort f2bf(float x) {
    __bf16 b = (__bf16)x;
    return __builtin_bit_cast(ushort, b);
}
static __device__ __forceinline__ float bf2f(ushort u) {
    return __uint_as_float(((unsigned)u) << 16);
}
static __device__ __forceinline__ void split1(float x, ushort& hi, ushort& lo) {
    __bf16 b = (__bf16)x;
    hi = __builtin_bit_cast(ushort, b);
    lo = __builtin_bit_cast(ushort, (__bf16)(x - (float)b));
}

// 3-product MFMA from subtile plane p (enc/dist)
#define MFMA_COMPUTE(p) do {                                                          \
    bf16x8 ah[4], al[4], bh[4], bl[4];                                                \
    _Pragma("unroll")                                                                 \
    for (int mi = 0; mi < 4; ++mi) {                                                  \
        const int off = (wm * 64 + mi * 16 + fr) * 32 + s4 * 8;                       \
        ah[mi] = *(const bf16x8*)&Ahs[p][off];                                        \
        al[mi] = *(const bf16x8*)&Als[p][off];                                        \
    }                                                                                 \
    _Pragma("unroll")                                                                 \
    for (int ni = 0; ni < 4; ++ni) {                                                  \
        const int off = (wn * 64 + ni * 16 + fr) * 32 + s4 * 8;                       \
        bh[ni] = *(const bf16x8*)&Bhs[p][off];                                        \
        bl[ni] = *(const bf16x8*)&Bls[p][off];                                        \
    }                                                                                 \
    _Pragma("unroll")                                                                 \
    for (int mi = 0; mi < 4; ++mi)                                                    \
        _Pragma("unroll")                                                             \
        for (int ni = 0; ni < 4; ++ni) {                                              \
            acc[mi][ni] = __builtin_amdgcn_mfma_f32_16x16x32_bf16(ah[mi], bh[ni], acc[mi][ni], 0, 0, 0); \
            acc[mi][ni] = __builtin_amdgcn_mfma_f32_16x16x32_bf16(ah[mi], bl[ni], acc[mi][ni], 0, 0, 0); \
            acc[mi][ni] = __builtin_amdgcn_mfma_f32_16x16x32_bf16(al[mi], bh[ni], acc[mi][ni], 0, 0, 0); \
        }                                                                             \
} while (0)

// 1-product MFMA (decoder: Qh x Wh)
#define MFMA_COMPUTE1(p) do {                                                         \
    bf16x8 ah[4], bh[4];                                                              \
    _Pragma("unroll")                                                                 \
    for (int mi = 0; mi < 4; ++mi) {                                                  \
        const int off = (wm * 64 + mi * 16 + fr) * 32 + s4 * 8;                       \
        ah[mi] = *(const bf16x8*)&Ahs[p][off];                                        \
    }                                                                                 \
    _Pragma("unroll")                                                                 \
    for (int ni = 0; ni < 4; ++ni) {                                                  \
        const int off = (wn * 64 + ni * 16 + fr) * 32 + s4 * 8;                       \
        bh[ni] = *(const bf16x8*)&Bhs[p][off];                                        \
    }                                                                                 \
    _Pragma("unroll")                                                                 \
    for (int mi = 0; mi < 4; ++mi)                                                    \
        _Pragma("unroll")                                                             \
        for (int ni = 0; ni < 4; ++ni)                                                \
            acc[mi][ni] = __builtin_amdgcn_mfma_f32_16x16x32_bf16(ah[mi], bh[ni], acc[mi][ni], 0, 0, 0); \
} while (0)

// ---------------- zero counters ----------------
__global__ __launch_bounds__(512)
void zero_kernel(unsigned* __restrict__ counts, float* __restrict__ loss_sum,
                 int* __restrict__ nflag) {
    counts[threadIdx.x] = 0u;
    if (threadIdx.x == 0) { loss_sum[0] = 0.f; nflag[0] = 0; }
}

// ---------------- numpy-pairwise sum of squares (fp32 input, for e_sq) --------
__global__ __launch_bounds__(256)
void sq_pairwise(const float* __restrict__ src, float* __restrict__ dst, int nrows) {
    int t = threadIdx.x;
    int row = blockIdx.x * 32 + (t >> 3);
    int j = t & 7;
    if (row >= nrows) return;
    const float* p = src + (size_t)row * C_DIM + j;
    float v = p[0];
    float r = __fmul_rn(v, v);
#pragma unroll
    for (int i = 1; i < 16; ++i) {
        float u = p[i * 8];
        r = __fadd_rn(r, __fmul_rn(u, u));
    }
    r = __fadd_rn(r, __shfl_xor(r, 1));
    r = __fadd_rn(r, __shfl_xor(r, 2));
    r = __fadd_rn(r, __shfl_xor(r, 4));
    if (j == 0) dst[row] = r;
}

// ---------------- split fp32 matrix into bf16 hi+lo ----------------
__global__ __launch_bounds__(256)
void split_hi_lo(const float* __restrict__ src, ushort* __restrict__ hi,
                 ushort* __restrict__ lo, int n4) {
    int e = blockIdx.x * 256 + threadIdx.x;
    if (e >= n4) return;
    float4 v = *(const float4*)&src[(size_t)e * 4];
    ushort4 H, L;
    split1(v.x, H.x, L.x); split1(v.y, H.y, L.y);
    split1(v.z, H.z, L.z); split1(v.w, H.w, L.w);
    *(ushort4*)&hi[(size_t)e * 4] = H;
    *(ushort4*)&lo[(size_t)e * 4] = L;
}

// ---------------- split fp32 matrix into bf16 hi only ----------------
__global__ __launch_bounds__(256)
void split_hi(const float* __restrict__ src, ushort* __restrict__ hi, int n4) {
    int e = blockIdx.x * 256 + threadIdx.x;
    if (e >= n4) return;
    float4 v = *(const float4*)&src[(size_t)e * 4];
    ushort4 H;
    H.x = f2bf(v.x); H.y = f2bf(v.y); H.z = f2bf(v.z); H.w = f2bf(v.w);
    *(ushort4*)&hi[(size_t)e * 4] = H;
}

// ---------------- encoder: split-bf16 MFMA GEMM, BK=64, fused xsq ----------
__global__ __launch_bounds__(256)
void enc_mfma(const float* __restrict__ h, const ushort* __restrict__ EWh,
              const ushort* __restrict__ EWl, const float* __restrict__ bias,
              ushort* __restrict__ Fh, ushort* __restrict__ Fl,
              float* __restrict__ xsq)
{
    constexpr int K = D_DIM, N = KC_DIM;
    __shared__ ushort Ahs[2][4096], Als[2][4096], Bhs[2][4096], Bls[2][4096];
    const int gid = blockIdx.x;                 // 1024 blocks
    const int f   = (gid & 7) * 128 + (gid >> 3);
    const int bx  = f & 3, by = f >> 2;         // 4 col-blocks, 256 row-blocks
    const int row0 = by * 128, col0 = bx * 128;
    const int tid  = threadIdx.x;
    const int lane = tid & 63, wave = tid >> 6;
    const int wm = wave >> 1, wn = wave & 1;

    f32x4 acc[4][4];
#pragma unroll
    for (int i = 0; i < 4; ++i)
#pragma unroll
        for (int j = 0; j < 4; ++j)
#pragma unroll
            for (int q = 0; q < 4; ++q) acc[i][j][q] = 0.f;

    const int fr = lane & 15, s4 = lane >> 4;
    const int arow = tid >> 3, ak8 = tid & 7;

#define ENC_STAGE(p, kt) do {                                                         \
    _Pragma("unroll")                                                                 \
    for (int r = 0; r < 2; ++r) {                                                     \
        const int t2 = r * 256 + wave * 64 + lane;                                    \
        const int ro = t2 >> 2, sb = t2 & 3;                                          \
        const int base = (r * 256 + wave * 64) * 8;                                   \
        const size_t gb = (size_t)(col0 + ro) * K + (kt) * 32 + sb * 8;               \
        __builtin_amdgcn_global_load_lds(AS1(EWh + gb), AS3(&Bhs[p][base]), 16, 0, 0);\
        __builtin_amdgcn_global_load_lds(AS1(EWl + gb), AS3(&Bls[p][base]), 16, 0, 0);\
    }                                                                                 \
    _Pragma("unroll")                                                                 \
    for (int q = 0; q < 4; ++q) {                                                     \
        const int row = q * 32 + arow;                                                \
        float4 v = *(const float4*)&h[(size_t)(row0 + row) * K + (kt) * 32 + ak8 * 4];\
        ushort4 H, L;                                                                 \
        split1(v.x, H.x, L.x); split1(v.y, H.y, L.y);                                 \
        split1(v.z, H.z, L.z); split1(v.w, H.w, L.w);                                 \
        *(ushort4*)&Ahs[p][row * 32 + ak8 * 4] = H;                                   \
        *(ushort4*)&Als[p][row * 32 + ak8 * 4] = L;                                   \
    }                                                                                 \
} while (0)

#pragma unroll 1
    for (int kt2 = 0; kt2 < K / 64; ++kt2) {    // 32 barrier periods
        ENC_STAGE(0, kt2 * 2);
        ENC_STAGE(1, kt2 * 2 + 1);
        __syncthreads();
        MFMA_COMPUTE(0);
        MFMA_COMPUTE(1);
        __syncthreads();
    }
#undef ENC_STAGE

    // epilogue: store split-bf16 flat + accumulate row sum-of-squares
    float ss[4][4];
#pragma unroll
    for (int mi = 0; mi < 4; ++mi)
#pragma unroll
        for (int q = 0; q < 4; ++q) ss[mi][q] = 0.f;

#pragma unroll
    for (int ni = 0; ni < 4; ++ni) {
        const int c = col0 + wn * 64 + ni * 16 + fr;
        const float bv = bias[c];
#pragma unroll
        for (int mi = 0; mi < 4; ++mi) {
            const int r = row0 + wm * 64 + mi * 16 + s4 * 4;
#pragma unroll
            for (int q = 0; q < 4; ++q) {
                float val = acc[mi][ni][q] + bv;
                ushort hi, lo;
                split1(val, hi, lo);
                size_t e = (size_t)(r + q) * N + c;
                Fh[e] = hi;
                Fl[e] = lo;
                ss[mi][q] += val * val;
            }
        }
    }
    // reduce ssq: 16 lanes (fr) per 16-group, then wn halves via LDS
    float* xpart = (float*)&Ahs[0][0];   // [128][2]
#pragma unroll
    for (int mi = 0; mi < 4; ++mi)
#pragma unroll
        for (int q = 0; q < 4; ++q) {
            float s = ss[mi][q];
            s += __shfl_xor(s, 1); s += __shfl_xor(s, 2);
            s += __shfl_xor(s, 4); s += __shfl_xor(s, 8);
            ss[mi][q] = s;
        }
    if (fr == 0) {
#pragma unroll
        for (int mi = 0; mi < 4; ++mi)
#pragma unroll
            for (int q = 0; q < 4; ++q)
                xpart[(wm * 64 + mi * 16 + s4 * 4 + q) * 2 + wn] = ss[mi][q];
    }
    __syncthreads();
    if (tid < 128)
        xsq[(size_t)(row0 + tid) * 4 + bx] = xpart[tid * 2] + xpart[tid * 2 + 1];
}

// ---------------- dist on matrix cores: all-bf16, BK=64 ----------
__global__ __launch_bounds__(256)
void dist_mfma(const ushort* __restrict__ Fh, const ushort* __restrict__ Fl,
               const ushort* __restrict__ cbh, const ushort* __restrict__ cbl,
               const float* __restrict__ xsq, const float* __restrict__ esq,
               float* __restrict__ pmin, float* __restrict__ psec,
               int* __restrict__ pidx)
{
    constexpr int K = C_DIM;                    // 128
    __shared__ ushort Ahs[2][4096], Als[2][4096], Bhs[2][4096], Bls[2][4096];
    const int gid = blockIdx.x;                 // 4096 blocks
    const int f   = (gid & 7) * 512 + (gid >> 3);
    const int bx  = f & 3, by = f >> 2;         // 4 col-blocks, 1024 row-blocks
    const int row0 = by * 128, col0 = bx * 128;
    const int tid  = threadIdx.x;
    const int lane = tid & 63, wave = tid >> 6;
    const int wm = wave >> 1, wn = wave & 1;

    f32x4 acc[4][4];
#pragma unroll
    for (int i = 0; i < 4; ++i)
#pragma unroll
        for (int j = 0; j < 4; ++j)
#pragma unroll
            for (int q = 0; q < 4; ++q) acc[i][j][q] = 0.f;

    const int fr = lane & 15, s4 = lane >> 4;

#define DIST_STAGE(p, kt) do {                                                        \
    _Pragma("unroll")                                                                 \
    for (int r = 0; r < 2; ++r) {                                                     \
        const int t2 = r * 256 + wave * 64 + lane;                                    \
        const int ro = t2 >> 2, sb = t2 & 3;                                          \
        const int base = (r * 256 + wave * 64) * 8;                                   \
        const size_t ga = (size_t)(row0 + ro) * K + (kt) * 32 + sb * 8;               \
        const size_t gb = (size_t)(col0 + ro) * K + (kt) * 32 + sb * 8;               \
        __builtin_amdgcn_global_load_lds(AS1(Fh + ga),  AS3(&Ahs[p][base]), 16, 0, 0);\
        __builtin_amdgcn_global_load_lds(AS1(Fl + ga),  AS3(&Als[p][base]), 16, 0, 0);\
        __builtin_amdgcn_global_load_lds(AS1(cbh + gb), AS3(&Bhs[p][base]), 16, 0, 0);\
        __builtin_amdgcn_global_load_lds(AS1(cbl + gb), AS3(&Bls[p][base]), 16, 0, 0);\
    }                                                                                 \
} while (0)

#pragma unroll 1
    for (int kt2 = 0; kt2 < K / 64; ++kt2) {    // 2 barrier periods
        DIST_STAGE(0, kt2 * 2);
        DIST_STAGE(1, kt2 * 2 + 1);
        __syncthreads();
        MFMA_COMPUTE(0);
        MFMA_COMPUTE(1);
        __syncthreads();
    }
#undef DIST_STAGE

    // epilogue: dist + per-row (best, second, idx). LDS scratch aliases Ahs/Als
    float* bB = (float*)&Ahs[0][0];          // [128][2]
    float* sB = (float*)&Ahs[0][0] + 256;    // [128][2]
    int*   iB = (int*)&Als[0][0];            // [128][2]

    float es_v[4];
#pragma unroll
    for (int ni = 0; ni < 4; ++ni) es_v[ni] = esq[col0 + wn * 64 + ni * 16 + fr];

#pragma unroll
    for (int mi = 0; mi < 4; ++mi) {
#pragma unroll
        for (int q = 0; q < 4; ++q) {
            const int r = wm * 64 + mi * 16 + s4 * 4 + q;
            const float xs = xsq[row0 + r];
            float b = FLT_BIG, s = FLT_BIG; int bi = 0;
#pragma unroll
            for (int ni = 0; ni < 4; ++ni) {
                float d = (xs - 2.0f * acc[mi][ni][q]) + es_v[ni];
                int c = col0 + wn * 64 + ni * 16 + fr;
                if (d < b) { s = b; b = d; bi = c; }
                else       { s = fminf(s, d); }
            }
#pragma unroll
            for (int m = 1; m < 16; m <<= 1) {
                float b2 = __shfl_xor(b, m);
                float s2 = __shfl_xor(s, m);
                int   i2 = __shfl_xor(bi, m);
                if (b2 < b || (b2 == b && i2 < bi)) { s = fminf(b, s2); b = b2; bi = i2; }
                else                                { s = fminf(s, b2); }
            }
            if (fr == 0) { bB[r * 2 + wn] = b; sB[r * 2 + wn] = s; iB[r * 2 + wn] = bi; }
        }
    }
    __syncthreads();
    if (tid < 128) {
        float b0 = bB[tid * 2],     s0 = sB[tid * 2];     int i0 = iB[tid * 2];
        float b1 = bB[tid * 2 + 1], s1 = sB[tid * 2 + 1]; int i1 = iB[tid * 2 + 1];
        float b, s; int ix;
        if (b1 < b0) { b = b1; s = fminf(b0, s1); ix = i1; }
        else         { b = b0; s = fminf(s0, b1); ix = i0; }
        size_t o = (size_t)(row0 + tid) * 4 + bx;
        pmin[o] = b; psec[o] = s; pidx[o] = ix;
    }
}

// ------- merge 4 col-blocks -> idx + flags + loss + histogram (pre-refine) ----
__global__ __launch_bounds__(256)
void merge_flag(const float* __restrict__ pmin, const float* __restrict__ psec,
                const int* __restrict__ pidx, int* __restrict__ idx_int,
                float* __restrict__ idx_f, int* __restrict__ rowlist,
                int* __restrict__ nflag, float* __restrict__ loss_sum,
                unsigned* __restrict__ counts) {
    __shared__ unsigned hist[NCODES];
    __shared__ float redf[256];
    int t = threadIdx.x;
    hist[t] = 0u; hist[t + 256] = 0u;
    __syncthreads();
    int row = blockIdx.x * 256 + t;
    size_t base = (size_t)row * 4;
    float b = pmin[base], sde = psec[base]; int ix = pidx[base];
#pragma unroll
    for (int nb = 1; nb < 4; ++nb) {
        float b2 = pmin[base + nb], s2 = psec[base + nb];
        if (b2 < b) { sde = fminf(b, s2); b = b2; ix = pidx[base + nb]; }
        else        { sde = fminf(sde, b2); }
    }
    idx_int[row] = ix;
    idx_f[row] = (float)ix;
    atomicAdd(&hist[ix], 1u);
    if (sde - b < GAP_EPS) {
        int p = atomicAdd(nflag, 1);
        rowlist[p] = row;
    }
    // loss: sum of min distances == sum_rows ||f - cb[idx]||^2
    redf[t] = b;
    __syncthreads();
    for (int st = 128; st; st >>= 1) {
        if (t < st) redf[t] += redf[t + st];
        __syncthreads();
    }
    if (t == 0) atomicAdd(loss_sum, redf[0]);
    if (hist[t]) atomicAdd(&counts[t], hist[t]);
    if (hist[t + 256]) atomicAdd(&counts[t + 256], hist[t + 256]);
}

// ---------------- exact recompute of near-tie rows + histogram correction -----
__global__ __launch_bounds__(256)
void refine_rows(const float* __restrict__ h, const float* __restrict__ enc_w,
                 const float* __restrict__ enc_b, const float* __restrict__ cb,
                 const float* __restrict__ esq, const int* __restrict__ rowlist,
                 const int* __restrict__ nflag_p, int* __restrict__ idx_int,
                 float* __restrict__ idx_f, unsigned* __restrict__ counts)
{
    __shared__ __align__(16) float x[C_DIM];
    __shared__ float xs_sh;
    __shared__ float rb[256];
    __shared__ int   ri[256];
    const int tid = threadIdx.x;
    const int nf = *nflag_p;
    for (int fi = blockIdx.x; fi < nf; fi += gridDim.x) {
        const int row = rowlist[fi];
        const int bt = row >> 2, seg = row & 3;
        if (tid < C_DIM) {
            const float* hp = h + (size_t)bt * D_DIM;
            const float* wp = enc_w + (size_t)(seg * C_DIM + tid) * D_DIM;
            float acc = 0.f, accC = 0.f;
            int fold = 96;   // 384/4
#pragma unroll 8
            for (int d = 0; d < D_DIM; d += 4) {
                float4 hv = *(const float4*)(hp + d);
                float4 wv = *(const float4*)(wp + d);
                accC = fmaf(hv.x, wv.x, accC);
                accC = fmaf(hv.y, wv.y, accC);
                accC = fmaf(hv.z, wv.z, accC);
                accC = fmaf(hv.w, wv.w, accC);
                if (--fold == 0) { acc = __fadd_rn(acc, accC); accC = 0.f; fold = 96; }
            }
            acc = __fadd_rn(acc, accC);   // K%384=128 remainder
            x[tid] = __fadd_rn(acc, enc_b[seg * C_DIM + tid]);
        }
        __syncthreads();
        if (tid == 0) {
            float rj[8];
#pragma unroll
            for (int j = 0; j < 8; ++j) rj[j] = __fmul_rn(x[j], x[j]);
            for (int i = 1; i < 16; ++i)
#pragma unroll
                for (int j = 0; j < 8; ++j)
                    rj[j] = __fadd_rn(rj[j], __fmul_rn(x[i * 8 + j], x[i * 8 + j]));
            float a01 = __fadd_rn(rj[0], rj[1]);
            float a23 = __fadd_rn(rj[2], rj[3]);
            float a45 = __fadd_rn(rj[4], rj[5]);
            float a67 = __fadd_rn(rj[6], rj[7]);
            xs_sh = __fadd_rn(__fadd_rn(a01, a23), __fadd_rn(a45, a67));
        }
        __syncthreads();
        const float xs = xs_sh;
        float best; int bi;
        {
            const int c0 = tid * 2;
            const float* e0 = cb + (size_t)c0 * C_DIM;
            float dot0 = 0.f, dot1 = 0.f;
#pragma unroll 4
            for (int c = 0; c < C_DIM; c += 4) {
                float4 xv  = *(const float4*)&x[c];
                float4 ev0 = *(const float4*)(e0 + c);
                float4 ev1 = *(const float4*)(e0 + C_DIM + c);
                dot0 = fmaf(xv.x, ev0.x, dot0); dot0 = fmaf(xv.y, ev0.y, dot0);
                dot0 = fmaf(xv.z, ev0.z, dot0); dot0 = fmaf(xv.w, ev0.w, dot0);
                dot1 = fmaf(xv.x, ev1.x, dot1); dot1 = fmaf(xv.y, ev1.y, dot1);
                dot1 = fmaf(xv.z, ev1.z, dot1); dot1 = fmaf(xv.w, ev1.w, dot1);
            }
            float d0 = __fadd_rn(__fsub_rn(xs, __fmul_rn(2.0f, dot0)), esq[c0]);
            float d1 = __fadd_rn(__fsub_rn(xs, __fmul_rn(2.0f, dot1)), esq[c0 + 1]);
            if (d1 < d0) { best = d1; bi = c0 + 1; } else { best = d0; bi = c0; }
        }
        rb[tid] = best; ri[tid] = bi;
        __syncthreads();
        for (int st = 128; st; st >>= 1) {
            if (tid < st) {
                float d2 = rb[tid + st]; int i2 = ri[tid + st];
                if (d2 < rb[tid] || (d2 == rb[tid] && i2 < ri[tid])) {
                    rb[tid] = d2; ri[tid] = i2;
                }
            }
            __syncthreads();
        }
        if (tid == 0) {
            int newi = ri[0];
            int oldi = idx_int[row];
            if (newi != oldi) {
                atomicSub(&counts[oldi], 1u);
                atomicAdd(&counts[newi], 1u);
                idx_int[row] = newi;
                idx_f[row] = (float)newi;
            }
        }
        __syncthreads();
    }
}

// ---------------- decoder: indirect-gather A (cbh via idx), 1-product, BK=64 --
__global__ __launch_bounds__(256)
void dec_gemm_bf16(const ushort* __restrict__ cbh, const int* __restrict__ idx,
                   const ushort* __restrict__ Wh, const float* __restrict__ bias,
                   float* __restrict__ C)
{
    constexpr int Kd = 512, Nd = 2048;
    __shared__ ushort Ahs[2][4096], Bhs[2][4096];
    __shared__ int idxL[512];
    const int gid = blockIdx.x;                       // 4096 blocks
    const int f   = (gid & 7) * 512 + (gid >> 3);
    const int bx  = f & 15, by = f >> 4;
    const int tid  = threadIdx.x;
    const int lane = tid & 63, wave = tid >> 6;
    const int wm = wave >> 1, wn = wave & 1;
    const int row0 = by * 128, col0 = bx * 128;

    idxL[tid]       = idx[(size_t)row0 * 4 + tid];
    idxL[tid + 256] = idx[(size_t)row0 * 4 + 256 + tid];

    f32x4 acc[4][4];
#pragma unroll
    for (int i = 0; i < 4; ++i)
#pragma unroll
        for (int j = 0; j < 4; ++j)
#pragma unroll
            for (int q = 0; q < 4; ++q) acc[i][j][q] = 0.f;

    const int fr = lane & 15, s4 = lane >> 4;
    __syncthreads();   // idxL ready

#define DEC_STAGE(p, kt) do {                                                         \
    _Pragma("unroll")                                                                 \
    for (int r = 0; r < 2; ++r) {                                                     \
        const int t2 = r * 256 + wave * 64 + lane;                                    \
        const int ro = t2 >> 2, sb = t2 & 3;                                          \
        const int base = (r * 256 + wave * 64) * 8;                                   \
        const int ci = idxL[ro * 4 + ((kt) >> 2)];                                    \
        const size_t ga = (size_t)ci * C_DIM + ((kt) & 3) * 32 + sb * 8;              \
        const size_t gb = (size_t)(col0 + ro) * Kd + (kt) * 32 + sb * 8;              \
        __builtin_amdgcn_global_load_lds(AS1(cbh + ga), AS3(&Ahs[p][base]), 16, 0, 0);\
        __builtin_amdgcn_global_load_lds(AS1(Wh + gb),  AS3(&Bhs[p][base]), 16, 0, 0);\
    }                                                                                 \
} while (0)

#pragma unroll 1
    for (int kt2 = 0; kt2 < Kd / 64; ++kt2) {   // 8 barrier periods
        DEC_STAGE(0, kt2 * 2);
        DEC_STAGE(1, kt2 * 2 + 1);
        __syncthreads();
        MFMA_COMPUTE1(0);
        MFMA_COMPUTE1(1);
        __syncthreads();
    }
#undef DEC_STAGE

#pragma unroll
    for (int ni = 0; ni < 4; ++ni) {
        const int c = col0 + wn * 64 + ni * 16 + fr;
        const float bv = bias[c];
#pragma unroll
        for (int mi = 0; mi < 4; ++mi) {
            const int r = row0 + wm * 64 + mi * 16 + s4 * 4;
#pragma unroll
            for (int q = 0; q < 4; ++q)
                C[(size_t)(r + q) * Nd + c] = acc[mi][ni][q] + bv;
        }
    }
}

// ---------------- scalars ----------------
__global__ __launch_bounds__(512)
void finalize_scalars(const unsigned* __restrict__ counts,
                      const float* __restrict__ loss_sum, float* __restrict__ out5) {
    __shared__ float rent[512];
    __shared__ float ruse[512];
    int t = threadIdx.x;
    float c = (float)counts[t];
    float avg = c * (1.0f / (float)NROWS);
    rent[t] = avg * logf(avg + 1e-10f);
    ruse[t] = counts[t] > 0u ? 1.f : 0.f;
    __syncthreads();
    for (int st = 256; st; st >>= 1) {
        if (t < st) { rent[t] += rent[t + st]; ruse[t] += ruse[t + st]; }
        __syncthreads();
    }
    if (t == 0) {
        float H = -rent[0];
        float perp = expf(H);
        float cl = loss_sum[0] * (1.0f / (float)NELEM);
        out5[0] = cl + 0.25f * cl;
        out5[1] = cl;
        out5[2] = cl;
        out5[3] = perp;
        out5[4] = ruse[0] * (1.0f / (float)NCODES);
    }
}

extern "C" void kernel_launch(void* const* d_in, const int* in_sizes, int n_in,
                              void* d_out, int out_size, void* d_ws, size_t ws_size,
                              hipStream_t stream) {
    const float* h     = (const float*)d_in[0];
    const float* enc_w = (const float*)d_in[1];
    const float* enc_b = (const float*)d_in[2];
    const float* cb    = (const float*)d_in[3];
    const float* dec_w = (const float*)d_in[4];
    const float* dec_b = (const float*)d_in[5];
    float* out = (float*)d_out;

    float* ws = (float*)d_ws;
    ushort*   Fh       = (ushort*)ws;                // [0, 8388608)f
    ushort*   Fl       = (ushort*)(ws + 8388608);    // [8388608, 16777216)f
    float*    xsq      = ws + 16777216;              // 131072 (dead after dist)
    float*    pmin     = ws + 16908288;              // 524288
    float*    psec     = ws + 17432576;              // 524288
    int*      pidx     = (int*)(ws + 17956864);      // 524288
    int*      idx_int  = (int*)(ws + 18481152);      // 131072
    float*    esq      = ws + 18743296;              // 512
    unsigned* counts   = (unsigned*)(ws + 18743808); // 512
    float*    loss_sum = ws + 18744320;              // 1
    int*      nflag    = (int*)(ws + 18744321);      // 1

    // overlays (hosts dead when used):
    ushort* EWh  = (ushort*)(ws + 16908288);         // over pmin  (pre-dist)
    ushort* EWl  = (ushort*)(ws + 17432576);         // over psec  (pre-dist)
    ushort* cbhd = (ushort*)(ws + 18612224);         // persistent cb-hi (dist + dec)
    ushort* cbld = (ushort*)(ws + 18644992);         // persistent cb-lo (dist)
    int*    rowlist = (int*)(ws + 16777216);         // over xsq (post-dist)
    ushort* Wh   = (ushort*)(ws + 16908288);         // over pmin (post-merge)

    float* msg_out = out;                     // 67108864
    float* idx_out = out + 67108864;          // 131072
    float* sc_out  = out + 67108864 + 131072; // 5

    zero_kernel<<<1, 512, 0, stream>>>(counts, loss_sum, nflag);
    sq_pairwise<<<NCODES / 32, 256, 0, stream>>>(cb, esq, NCODES);

    split_hi_lo<<<KC_DIM * D_DIM / 4 / 256, 256, 0, stream>>>(enc_w, EWh, EWl, KC_DIM * D_DIM / 4);
    split_hi_lo<<<NCODES * C_DIM / 4 / 256, 256, 0, stream>>>(cb, cbhd, cbld, NCODES * C_DIM / 4);

    // encoder on matrix cores (BK=64) -> split-bf16 flat planes + fused xsq
    enc_mfma<<<1024, 256, 0, stream>>>(h, EWh, EWl, enc_b, Fh, Fl, xsq);

    // distances on matrix cores (BK=64) + best/second/idx
    dist_mfma<<<4096, 256, 0, stream>>>(Fh, Fl, cbhd, cbld, xsq, esq, pmin, psec, pidx);

    // merge: final idx + flags + loss + pre-refine histogram
    merge_flag<<<NROWS / 256, 256, 0, stream>>>(pmin, psec, pidx, idx_int, idx_out,
                                                rowlist, nflag, loss_sum, counts);

    // exact recompute for near-tie rows (corrects idx + histogram deltas)
    refine_rows<<<2048, 256, 0, stream>>>(h, enc_w, enc_b, cb, esq, rowlist, nflag,
                                          idx_int, idx_out, counts);

    // decoder weight split (pmin dead after merge)
    split_hi<<<D_DIM * KC_DIM / 4 / 256, 256, 0, stream>>>(dec_w, Wh, D_DIM * KC_DIM / 4);

    // decoder (BK=64, 1-product, indirect A-gather from cbhd)
    dec_gemm_bf16<<<4096, 256, 0, stream>>>(cbhd, idx_int, Wh, dec_b, msg_out);

    finalize_scalars<<<1, 512, 0, stream>>>(counts, loss_sum, sc_out);
}